// Round 5
// baseline (303.267 us; speedup 1.0000x reference)
//
#include <hip/hip_runtime.h>
#include <hip/hip_bf16.h>

// SEAL GCN: 3x GraphConv(norm=both) -> SumPool(graph_id sorted) -> MLP(128->128 relu ->200)
// N=50000, E=800000, feat=128, 512 graphs.
// R15: chunked-feature gather (4 x 32-feat chunks, x stored [4][N+1][32] bf16) so the
//      instantaneous working set (3.2MB) fits one XCD L2 (4MB) -> random x reads become
//      L2 hits (R2-R4 evidence: FETCH 73MB/gather, latency wall immune to occupancy).
//      CSR rows padded to 16 entries pointing at zero row N: branch-free 16-wide inner
//      loop, broadcast uint4 csr loads + and/shift extraction (no shfl round-trip).
//      CH 128->256 (fill scatter used half the CUs); x0 build split into no-LDS kernel.

#define FEAT 128
#define NG 512
#define CH 256       // edge chunks for hist/fill
#define SEG (CH / 8) // chunks per scan segment in k_merge
#define NPMAX 12544  // max node-quads (N<=50176); 50KB static LDS
#define LDW 136      // LDS row stride in ushorts (bf16): 2-way-free banks for b128

typedef __attribute__((ext_vector_type(8))) short bf16x8;
typedef __attribute__((ext_vector_type(4))) float f32x4;

__device__ __forceinline__ unsigned short f2bf(float f) {
    unsigned int u = __float_as_uint(f);
    return (unsigned short)((u + 0x7FFFu + ((u >> 16) & 1u)) >> 16);  // RNE
}
__device__ __forceinline__ float lo16(unsigned u) { return __uint_as_float(u << 16); }
__device__ __forceinline__ float hi16(unsigned u) { return __uint_as_float(u & 0xFFFF0000u); }

// ---------------- chunked full-range histogram, packed u8, zero global atomics ----------------
__global__ __launch_bounds__(256) void k_hist(
        const int* __restrict__ src, const int* __restrict__ dst,
        unsigned* __restrict__ partial_out, unsigned* __restrict__ partial_in,
        int E, int NP, int Ec) {
    __shared__ unsigned h[NPMAX];
    int tid = threadIdx.x;
    int b = blockIdx.x;
    int c = b & (CH - 1);
    const int* __restrict__ arr = (b < CH) ? src : dst;
    unsigned* __restrict__ outp = ((b < CH) ? partial_out : partial_in) + (size_t)c * NP;
    for (int i = tid; i < NP; i += 256) h[i] = 0;
    __syncthreads();
    int e0 = c * Ec, e1 = min(E, e0 + Ec);
    for (int e = e0 + tid; e < e1; e += 256) {
        int v = arr[e];
        atomicAdd(&h[v >> 2], 1u << ((v & 3) * 8));
    }
    __syncthreads();
    for (int i = tid; i < NP; i += 256) outp[i] = h[i];
}

// ---------------- merge partials: tiled parallel scan (32 quads x CH chunks / block) ----------
__global__ __launch_bounds__(256) void k_merge(
        unsigned* __restrict__ partial_out, unsigned* __restrict__ partial_in,
        int* __restrict__ cnt_in, float* __restrict__ norm_out,
        float* __restrict__ norm_in, int N, int NP) {
    __shared__ unsigned tile[CH][33];   // 256 x 33 u32 = 33.8KB
    __shared__ unsigned sums[32][9];    // [quad][seg 0..7, total_in at 8]
    int q0 = blockIdx.x * 32;
    int tid = threadIdx.x;
    int qd = tid & 31, k = tid >> 5;

    // ---- pass 1: partial_in -> exclusive prefix + totals ----
    for (int idx = tid; idx < 32 * CH; idx += 256) {
        int c = idx >> 5, q = idx & 31;
        unsigned v = 0;
        if (q0 + q < NP) v = partial_in[(size_t)c * NP + q0 + q];
        tile[c][q] = v;
    }
    __syncthreads();
    unsigned loc = 0;
    #pragma unroll
    for (int i = 0; i < SEG; i++) loc += tile[k * SEG + i][qd];
    sums[qd][k] = loc;
    __syncthreads();
    if (k == 0) {
        unsigned r = 0;
        #pragma unroll
        for (int j = 0; j < 8; j++) { unsigned v = sums[qd][j]; sums[qd][j] = r; r += v; }
        sums[qd][8] = r;   // total in-degree (packed u8 x4)
    }
    __syncthreads();
    unsigned run = sums[qd][k];
    #pragma unroll
    for (int i = 0; i < SEG; i++) {
        unsigned v = tile[k * SEG + i][qd];
        tile[k * SEG + i][qd] = run;
        run += v;
    }
    __syncthreads();
    for (int idx = tid; idx < 32 * CH; idx += 256) {
        int c = idx >> 5, q = idx & 31;
        if (q0 + q < NP) partial_in[(size_t)c * NP + q0 + q] = tile[c][q];
    }
    __syncthreads();

    // ---- pass 2: partial_out totals only ----
    for (int idx = tid; idx < 32 * CH; idx += 256) {
        int c = idx >> 5, q = idx & 31;
        unsigned v = 0;
        if (q0 + q < NP) v = partial_out[(size_t)c * NP + q0 + q];
        tile[c][q] = v;
    }
    __syncthreads();
    unsigned loco = 0;
    #pragma unroll
    for (int i = 0; i < SEG; i++) loco += tile[k * SEG + i][qd];
    sums[qd][k] = loco;
    __syncthreads();
    if (k == 0) {
        unsigned tot = 0;
        #pragma unroll
        for (int j = 0; j < 8; j++) tot += sums[qd][j];
        unsigned rin = sums[qd][8];
        int w = q0 + qd;
        if (w < NP) {
            #pragma unroll
            for (int j = 0; j < 4; j++) {
                int node = w * 4 + j;
                if (node < N) {
                    unsigned di = (rin >> (j * 8)) & 255u;
                    unsigned dd = (tot >> (j * 8)) & 255u;
                    cnt_in[node]   = (int)di;
                    norm_in[node]  = rsqrtf(fmaxf((float)di, 1.0f));
                    norm_out[node] = rsqrtf(fmaxf((float)dd, 1.0f));
                }
            }
        }
    }
}

// ---------------- 2-level exclusive scan of PADDED counts -> row_start ----------------
// rows padded to 16 entries (pads -> zero row) for the branch-free gather.
__global__ void k_scan_local(const int* __restrict__ cnt, int* __restrict__ excl,
                             int* __restrict__ bsum, int N) {
    __shared__ int s[256];
    int x = threadIdx.x;
    int i = blockIdx.x * 256 + x;
    int v = (i < N) ? ((cnt[i] + 15) & ~15) : 0;
    s[x] = v;
    __syncthreads();
    for (int off = 1; off < 256; off <<= 1) {
        int t = (x >= off) ? s[x - off] : 0;
        __syncthreads();
        s[x] += t;
        __syncthreads();
    }
    if (i < N) excl[i] = s[x] - v;
    if (x == 255) bsum[blockIdx.x] = s[255];
}

// block 0: scan of block sums; blocks 1..128: pack W0,W1 -> bf16 MFMA B-fragment order
__global__ void k_scan_bsum_prep(int* __restrict__ bsum, int* __restrict__ boff, int nb,
                                 const float* __restrict__ W0, const float* __restrict__ W1,
                                 unsigned short* __restrict__ WF0, unsigned short* __restrict__ WF1) {
    if (blockIdx.x == 0) {
        __shared__ int s[256];
        int x = threadIdx.x;
        int v = (x < nb) ? bsum[x] : 0;
        s[x] = v;
        __syncthreads();
        for (int off = 1; off < 256; off <<= 1) {
            int t = (x >= off) ? s[x - off] : 0;
            __syncthreads();
            s[x] += t;
            __syncthreads();
        }
        if (x < nb) boff[x] = s[x] - v;
    } else {
        int t = ((int)blockIdx.x - 1) * 256 + threadIdx.x;  // 0..32767
        const float* __restrict__ W = (t < 16384) ? W0 : W1;
        unsigned short* __restrict__ WF = (t < 16384) ? WF0 : WF1;
        int tt = t & 16383;
        int f = tt >> 9, l = (tt >> 3) & 63, e = tt & 7;
        int n = (f >> 2) * 16 + (l & 15);
        int k = (f & 3) * 32 + (l >> 4) * 8 + e;
        WF[tt] = f2bf(W[k * 128 + n]);
    }
}

// row_start += boff; zero pooled accum g; init csr pads to N; zero the zero-rows of xA/xB
__global__ void k_add_off(int* __restrict__ row_start, const int* __restrict__ boff,
                          float* __restrict__ g, unsigned short* __restrict__ csr,
                          unsigned short* __restrict__ xA, unsigned short* __restrict__ xB,
                          int N, int csrtot) {
    int i = blockIdx.x * blockDim.x + threadIdx.x;
    int stride = gridDim.x * blockDim.x;
    size_t CSU = (size_t)(N + 1) * 32;
    if (i < N) row_start[i] += boff[i >> 8];
    for (int j = i; j < NG * FEAT; j += stride) g[j] = 0.f;
    for (int j = i; j < csrtot; j += stride) csr[j] = (unsigned short)N;
    for (int j = i; j < 256; j += stride) {
        unsigned short* xp = (j < 128) ? xA : xB;
        int c = (j >> 5) & 3, kk = j & 31;
        xp[(size_t)c * CSU + (size_t)N * 32 + kk] = 0;
    }
}

// ---------------- chunked CSR fill (LDS cursors, packed u8, u16 csr) ----------------
__global__ __launch_bounds__(256) void k_fill(
        const int* __restrict__ src, const int* __restrict__ dst,
        const int* __restrict__ row_start, const unsigned* __restrict__ partial_in,
        unsigned short* __restrict__ csr, int N, int E, int NP, int Ec) {
    __shared__ unsigned cur[NPMAX];
    int tid = threadIdx.x;
    int c = blockIdx.x;
    const unsigned* __restrict__ pre = partial_in + (size_t)c * NP;
    for (int i = tid; i < NP; i += 256) cur[i] = pre[i];
    __syncthreads();
    int e0 = c * Ec, e1 = min(E, e0 + Ec);
    for (int e = e0 + tid; e < e1; e += 256) {
        int d = dst[e], s = src[e];
        int sh = (d & 3) * 8;
        unsigned t = atomicAdd(&cur[d >> 2], 1u << sh);
        int off = (int)((t >> sh) & 255u);
        csr[row_start[d] + off] = (unsigned short)s;
    }
}

// ---------------- x0 build (chunked layout), full occupancy (no LDS) ----------------
__global__ __launch_bounds__(256) void k_build_x(
        const int* __restrict__ nid, const int* __restrict__ z,
        const float* __restrict__ emb, const float* __restrict__ zt,
        const float* __restrict__ nout, unsigned short* __restrict__ x, int N) {
    int t = blockIdx.x * 256 + threadIdx.x;
    int i = t >> 5, q = t & 31;
    if (i >= N) return;
    size_t CSU = (size_t)(N + 1) * 32;
    float4 v;
    if (q < 16) v = ((const float4*)emb)[(size_t)nid[i] * 16 + q];
    else        v = ((const float4*)zt)[(size_t)z[i] * 16 + (q - 16)];
    float w = nout[i];
    ushort4 u;
    u.x = f2bf(v.x * w); u.y = f2bf(v.y * w);
    u.z = f2bf(v.z * w); u.w = f2bf(v.w * w);
    int cch = q >> 3;            // feats q*4.. -> chunk (q*4)>>5
    int wi = (q * 4) & 31;
    *(ushort4*)(x + (size_t)cch * CSU + (size_t)i * 32 + wi) = u;
}

// ---------------- branch-free chunked gather: 16 lanes/node, 32 feats (chunk P) ----------------
// cp: broadcast uint4 loads of 16 u16 csr entries (rows 16-padded to zero row N).
// xch: (const unsigned*)x + ql ; chunk stride CS2 = (N+1)*16 uints; row = 16 uints.
#define ACCU(u, A0, A1) A0 += lo16(u); A1 += hi16(u);
#define GATHER_CHUNK(P, A0, A1)                                                  \
    {                                                                            \
        const unsigned* __restrict__ xq = xch + (size_t)(P) * CS2;               \
        for (int j0 = 0; j0 < n; j0 += 16) {                                     \
            uint4 qa = cp[(j0 >> 3)];                                            \
            uint4 qb = cp[(j0 >> 3) + 1];                                        \
            unsigned u0  = xq[(qa.x & 0xFFFFu) * 16];                            \
            unsigned u1  = xq[(qa.x >> 16) * 16];                                \
            unsigned u2  = xq[(qa.y & 0xFFFFu) * 16];                            \
            unsigned u3  = xq[(qa.y >> 16) * 16];                                \
            unsigned u4  = xq[(qa.z & 0xFFFFu) * 16];                            \
            unsigned u5  = xq[(qa.z >> 16) * 16];                                \
            unsigned u6  = xq[(qa.w & 0xFFFFu) * 16];                            \
            unsigned u7  = xq[(qa.w >> 16) * 16];                                \
            unsigned u8  = xq[(qb.x & 0xFFFFu) * 16];                            \
            unsigned u9  = xq[(qb.x >> 16) * 16];                                \
            unsigned u10 = xq[(qb.y & 0xFFFFu) * 16];                            \
            unsigned u11 = xq[(qb.y >> 16) * 16];                                \
            unsigned u12 = xq[(qb.z & 0xFFFFu) * 16];                            \
            unsigned u13 = xq[(qb.z >> 16) * 16];                                \
            unsigned u14 = xq[(qb.w & 0xFFFFu) * 16];                            \
            unsigned u15 = xq[(qb.w >> 16) * 16];                                \
            ACCU(u0, A0, A1)  ACCU(u1, A0, A1)  ACCU(u2, A0, A1)  ACCU(u3, A0, A1)   \
            ACCU(u4, A0, A1)  ACCU(u5, A0, A1)  ACCU(u6, A0, A1)  ACCU(u7, A0, A1)   \
            ACCU(u8, A0, A1)  ACCU(u9, A0, A1)  ACCU(u10, A0, A1) ACCU(u11, A0, A1)  \
            ACCU(u12, A0, A1) ACCU(u13, A0, A1) ACCU(u14, A0, A1) ACCU(u15, A0, A1)  \
        }                                                                        \
    }

#define GATHER_ALL                                                               \
    int base = row_start[node];                                                  \
    int n = cnt_in[node];                                                        \
    const uint4* __restrict__ cp = (const uint4*)(csr + base);                   \
    const unsigned* __restrict__ xch = (const unsigned*)x + ql;                  \
    const size_t CS2 = (size_t)(N + 1) * 16;                                     \
    GATHER_CHUNK(0, c0a, c0b)                                                    \
    GATHER_CHUNK(1, c1a, c1b)                                                    \
    GATHER_CHUNK(2, c2a, c2b)                                                    \
    GATHER_CHUNK(3, c3a, c3b)

// ---------------- fused gather + MFMA GEMM, 16 nodes/block ----------------
__global__ __launch_bounds__(256) void k_gather_gemm(
        const unsigned short* __restrict__ x, const float* __restrict__ nin,
        const unsigned short* __restrict__ csr, const int* __restrict__ row_start,
        const int* __restrict__ cnt_in, const unsigned short* __restrict__ WF,
        const float* __restrict__ bias, const float* __restrict__ nout,
        unsigned short* __restrict__ y, int N) {
    __shared__ unsigned short As[16 * LDW];  // 4.3KB
    int tid = threadIdx.x;
    int nb = blockIdx.x * 16;
    int ql = tid & 15;
    int nl = tid >> 4;
    int node = nb + nl;

    float c0a = 0.f, c0b = 0.f, c1a = 0.f, c1b = 0.f;
    float c2a = 0.f, c2b = 0.f, c3a = 0.f, c3b = 0.f;
    if (node < N) {
        GATHER_ALL
        float ni = nin[node];
        c0a *= ni; c0b *= ni; c1a *= ni; c1b *= ni;
        c2a *= ni; c2b *= ni; c3a *= ni; c3b *= ni;
    }
    // lane ql holds feats {p*32+ql*2, +1}: write 4 packed uints into row-major As
    unsigned short* ar = As + nl * LDW + ql * 2;
    *(unsigned*)(ar +  0) = (unsigned)f2bf(c0a) | ((unsigned)f2bf(c0b) << 16);
    *(unsigned*)(ar + 32) = (unsigned)f2bf(c1a) | ((unsigned)f2bf(c1b) << 16);
    *(unsigned*)(ar + 64) = (unsigned)f2bf(c2a) | ((unsigned)f2bf(c2b) << 16);
    *(unsigned*)(ar + 96) = (unsigned)f2bf(c3a) | ((unsigned)f2bf(c3b) << 16);
    __syncthreads();

    int lane = tid & 63;
    int wv = tid >> 6;
    int c = lane & 15, q = lane >> 4;

    // shared 16-row A-fragments (identical across waves: LDS broadcast)
    const unsigned short* ap = As + c * LDW + q * 8;
    bf16x8 fa0 = *(const bf16x8*)(ap);
    bf16x8 fa1 = *(const bf16x8*)(ap + 32);
    bf16x8 fa2 = *(const bf16x8*)(ap + 64);
    bf16x8 fa3 = *(const bf16x8*)(ap + 96);
    const bf16x8* __restrict__ wf = (const bf16x8*)WF;
    __syncthreads();  // A-frags in regs; safe to overwrite As with outputs

    #pragma unroll
    for (int t = 0; t < 2; t++) {
        int nt = wv * 2 + t;
        bf16x8 fb0 = wf[(nt * 4 + 0) * 64 + lane];
        bf16x8 fb1 = wf[(nt * 4 + 1) * 64 + lane];
        bf16x8 fb2 = wf[(nt * 4 + 2) * 64 + lane];
        bf16x8 fb3 = wf[(nt * 4 + 3) * 64 + lane];
        float bb = bias[nt * 16 + c];
        f32x4 acc = {bb, bb, bb, bb};
        acc = __builtin_amdgcn_mfma_f32_16x16x32_bf16(fa0, fb0, acc, 0, 0, 0);
        acc = __builtin_amdgcn_mfma_f32_16x16x32_bf16(fa1, fb1, acc, 0, 0, 0);
        acc = __builtin_amdgcn_mfma_f32_16x16x32_bf16(fa2, fb2, acc, 0, 0, 0);
        acc = __builtin_amdgcn_mfma_f32_16x16x32_bf16(fa3, fb3, acc, 0, 0, 0);
        #pragma unroll
        for (int rr = 0; rr < 4; rr++) {
            int row = q * 4 + rr;
            float s = nout[min(nb + row, N - 1)];
            As[row * LDW + nt * 16 + c] = f2bf(fmaxf(acc[rr], 0.f) * s);
        }
    }
    __syncthreads();

    // store 16 rows x 128 u16 into chunked layout y[4][N+1][32]
    {
        size_t CSU = (size_t)(N + 1) * 32;
        int row = tid >> 4, seg = tid & 15;     // seg: 8-feat group
        int nd = nb + row;
        if (nd < N) {
            int cch = seg >> 2, wi = (seg & 3) * 8;
            const ushort4* p = (const ushort4*)(As + row * LDW + seg * 8);
            ushort4* d = (ushort4*)(y + (size_t)cch * CSU + (size_t)nd * 32 + wi);
            d[0] = p[0]; d[1] = p[1];
        }
    }
}

// ---------------- fused layer-2 gather + SumPool ----------------
__global__ __launch_bounds__(256) void k_gather_pool(
        const unsigned short* __restrict__ x, const float* __restrict__ nin,
        const unsigned short* __restrict__ csr, const int* __restrict__ row_start,
        const int* __restrict__ cnt_in, const int* __restrict__ gid,
        float* __restrict__ g, int N) {
    __shared__ __align__(16) float gl[16][132];  // per-node partials, +4 pad
    __shared__ int slots[16];
    int tid = threadIdx.x;
    int nb = blockIdx.x * 16;
    int ql = tid & 15;
    int nl = tid >> 4;
    int node = nb + nl;

    float c0a = 0.f, c0b = 0.f, c1a = 0.f, c1b = 0.f;
    float c2a = 0.f, c2b = 0.f, c3a = 0.f, c3b = 0.f;
    int slot = -1;
    if (node < N) {
        GATHER_ALL
        float ni = nin[node];
        c0a *= ni; c0b *= ni; c1a *= ni; c1b *= ni;
        c2a *= ni; c2b *= ni; c3a *= ni; c3b *= ni;
        slot = gid[node];
    }
    {
        float2* r0 = (float2*)&gl[nl][ql * 2];
        r0[0]  = make_float2(c0a, c0b);          // feats  0+ql*2
        *(float2*)&gl[nl][32 + ql * 2] = make_float2(c1a, c1b);
        *(float2*)&gl[nl][64 + ql * 2] = make_float2(c2a, c2b);
        *(float2*)&gl[nl][96 + ql * 2] = make_float2(c3a, c3b);
    }
    if (ql == 0) slots[nl] = slot;
    __syncthreads();

    int h = tid >> 7;       // 0/1: nodes 0-7 / 8-15
    int j = tid & 127;
    int prev = -1;
    float acc = 0.f;
    #pragma unroll
    for (int i = h * 8; i < h * 8 + 8; i++) {
        int s = slots[i];
        if (s != prev) {
            if (prev >= 0) atomicAdd(&g[(size_t)prev * FEAT + j], acc);
            acc = 0.f;
            prev = s;
        }
        acc += gl[i][j];
    }
    if (prev >= 0) atomicAdd(&g[(size_t)prev * FEAT + j], acc);
}

// ---------------- head: ys = g@W2 + cnt*b2 ; out = relu(ys@l1W+l1b)@l2W+l2b ----------------
__global__ __launch_bounds__(256) void k_head(
        const float* __restrict__ g, const int* __restrict__ gid,
        const float* __restrict__ W2, const float* __restrict__ b2,
        const float* __restrict__ l1W, const float* __restrict__ l1b,
        const float* __restrict__ l2W, const float* __restrict__ l2b,
        float* __restrict__ out, int N) {
    __shared__ float gs[128];
    __shared__ float ys[128];
    __shared__ float hs[128];
    int gi = blockIdx.x, tid = threadIdx.x;

    int lo = 0, hi = N;
    while (lo < hi) { int m = (lo + hi) >> 1; if (gid[m] < gi) lo = m + 1; else hi = m; }
    int s0 = lo;
    lo = 0; hi = N;
    while (lo < hi) { int m = (lo + hi) >> 1; if (gid[m] < gi + 1) lo = m + 1; else hi = m; }
    float cnt = (float)(lo - s0);

    if (tid < 128) gs[tid] = g[(size_t)gi * FEAT + tid];
    __syncthreads();
    if (tid < 128) {
        float a = cnt * b2[tid];
        for (int k = 0; k < 128; k++) a += gs[k] * W2[(size_t)k * 128 + tid];
        ys[tid] = a;
    }
    __syncthreads();
    if (tid < 128) {
        float a = l1b[tid];
        for (int k = 0; k < 128; k++) a += ys[k] * l1W[(size_t)k * 128 + tid];
        hs[tid] = fmaxf(a, 0.f);
    }
    __syncthreads();
    if (tid < 200) {
        float a = l2b[tid];
        for (int k = 0; k < 128; k++) a += hs[k] * l2W[(size_t)k * 200 + tid];
        out[(size_t)gi * 200 + tid] = a;
    }
}

extern "C" void kernel_launch(void* const* d_in, const int* in_sizes, int n_in,
                              void* d_out, int out_size, void* d_ws, size_t ws_size,
                              hipStream_t stream) {
    const int*   nid = (const int*)d_in[0];
    const int*   z   = (const int*)d_in[1];
    const int*   src = (const int*)d_in[2];
    const int*   dst = (const int*)d_in[3];
    const int*   gid = (const int*)d_in[4];
    const float* emb = (const float*)d_in[5];
    const float* zt  = (const float*)d_in[6];
    const float* W0  = (const float*)d_in[7];
    const float* b0  = (const float*)d_in[8];
    const float* W1  = (const float*)d_in[9];
    const float* b1  = (const float*)d_in[10];
    const float* W2  = (const float*)d_in[11];
    const float* b2  = (const float*)d_in[12];
    const float* l1W = (const float*)d_in[13];
    const float* l1b = (const float*)d_in[14];
    const float* l2W = (const float*)d_in[15];
    const float* l2b = (const float*)d_in[16];
    float* out = (float*)d_out;

    const int N = in_sizes[0];
    const int E = in_sizes[2];
    const int NB = (N + 255) / 256;     // scan blocks (<=256 required)
    const int NP = (N + 3) / 4;         // node-quads (<= NPMAX)
    const int Ec = (E + CH - 1) / CH;   // edges per chunk
    const int CSRTOT = E + 16 * N + 64; // padded csr capacity (u16)
    const size_t XSZ = (size_t)4 * (N + 1) * 32;  // chunked x: [4][N+1][32] u16

    // ---- workspace ----
    size_t NA = (size_t)((N + 63) & ~63);
    float* norm_out = (float*)d_ws;                      // NA
    float* norm_in  = norm_out + NA;                     // NA
    float* g        = norm_in + NA;                      // NG*FEAT fp32 pooled accum
    unsigned short* xA  = (unsigned short*)(g + (size_t)NG * FEAT);  // XSZ
    unsigned short* xB  = xA + XSZ;                      // XSZ
    unsigned short* WF0 = xB + XSZ;                      // 128*128 bf16 (fragment order)
    unsigned short* WF1 = WF0 + 128 * 128;               // 128*128 bf16
    int* cnt_in    = (int*)(WF1 + 128 * 128);            // NA
    int* row_start = cnt_in + NA;                        // NA
    int* bsum      = row_start + NA;                     // 256
    int* boff      = bsum + 256;                         // 256
    unsigned* partial_out = (unsigned*)(boff + 256);     // CH*NP
    unsigned* partial_in  = partial_out + (size_t)CH * NP; // CH*NP
    unsigned short* csr = (unsigned short*)(partial_in + (size_t)CH * NP); // CSRTOT u16

    // ---- atomic-free CSR build + norms + W fragment packs ----
    k_hist<<<2 * CH, 256, 0, stream>>>(src, dst, partial_out, partial_in, E, NP, Ec);
    k_merge<<<(NP + 31) / 32, 256, 0, stream>>>(partial_out, partial_in, cnt_in,
                                                norm_out, norm_in, N, NP);
    k_scan_local<<<NB, 256, 0, stream>>>(cnt_in, row_start, bsum, N);
    k_scan_bsum_prep<<<1 + 128, 256, 0, stream>>>(bsum, boff, NB, W0, W1, WF0, WF1);
    k_add_off<<<NB, 256, 0, stream>>>(row_start, boff, g, csr, xA, xB, N, CSRTOT);
    k_build_x<<<(N * 32 + 255) / 256, 256, 0, stream>>>(nid, z, emb, zt, norm_out, xA, N);
    k_fill<<<CH, 256, 0, stream>>>(src, dst, row_start, partial_in, csr, N, E, NP, Ec);

    int gg_blocks = (N + 15) / 16;

    // layer 0: xA -> xB (fused chunked gather + GEMM, 16 nodes/block)
    k_gather_gemm<<<gg_blocks, 256, 0, stream>>>(xA, norm_in, csr, row_start, cnt_in,
                                                 WF0, b0, norm_out, xB, N);
    // layer 1: xB -> xA
    k_gather_gemm<<<gg_blocks, 256, 0, stream>>>(xB, norm_in, csr, row_start, cnt_in,
                                                 WF1, b1, norm_out, xA, N);
    // layer 2: gather fused with SumPool (GEMM commuted past pool via linearity)
    k_gather_pool<<<gg_blocks, 256, 0, stream>>>(xA, norm_in, csr, row_start, cnt_in,
                                                 gid, g, N);

    // tiny per-graph MLP head
    k_head<<<NG, 256, 0, stream>>>(g, gid, W2, b2, l1W, l1b, l2W, l2b, out, N);
}

// Round 7
// 285.097 us; speedup vs baseline: 1.0637x; 1.0637x over previous
//
#include <hip/hip_runtime.h>
#include <hip/hip_bf16.h>

// SEAL GCN: 3x GraphConv(norm=both) -> SumPool(graph_id sorted) -> MLP(128->128 relu ->200)
// N=50000, E=800000, feat=128, 512 graphs.
// R17 (= R16 resubmit; R6 bench was an infra failure, not a kernel verdict):
//      padded CSR (rows ->16 mult, pads hit zero row N) enabling branch-free gather with
//      broadcast uint4 csr loads + bitfield extract (no shfl chains), split no-LDS
//      k_build_x, CH=256 fill parallelism. x row-major [N+1][128] bf16, 16B/lane gather.

#define FEAT 128
#define NG 512
#define CH 256       // edge chunks for hist/fill
#define SEG (CH / 8) // chunks per scan segment in k_merge
#define NPMAX 12544  // max node-quads (N<=50176); 50KB static LDS
#define LDW 136      // LDS row stride in ushorts (bf16): 2-way-free banks for b128

typedef __attribute__((ext_vector_type(8))) short bf16x8;
typedef __attribute__((ext_vector_type(4))) float f32x4;

__device__ __forceinline__ unsigned short f2bf(float f) {
    unsigned int u = __float_as_uint(f);
    return (unsigned short)((u + 0x7FFFu + ((u >> 16) & 1u)) >> 16);  // RNE
}
__device__ __forceinline__ float lo16(unsigned u) { return __uint_as_float(u << 16); }
__device__ __forceinline__ float hi16(unsigned u) { return __uint_as_float(u & 0xFFFF0000u); }

// ---------------- chunked full-range histogram, packed u8, zero global atomics ----------------
__global__ __launch_bounds__(256) void k_hist(
        const int* __restrict__ src, const int* __restrict__ dst,
        unsigned* __restrict__ partial_out, unsigned* __restrict__ partial_in,
        int E, int NP, int Ec) {
    __shared__ unsigned h[NPMAX];
    int tid = threadIdx.x;
    int b = blockIdx.x;
    int c = b & (CH - 1);
    const int* __restrict__ arr = (b < CH) ? src : dst;
    unsigned* __restrict__ outp = ((b < CH) ? partial_out : partial_in) + (size_t)c * NP;
    for (int i = tid; i < NP; i += 256) h[i] = 0;
    __syncthreads();
    int e0 = c * Ec, e1 = min(E, e0 + Ec);
    for (int e = e0 + tid; e < e1; e += 256) {
        int v = arr[e];
        atomicAdd(&h[v >> 2], 1u << ((v & 3) * 8));
    }
    __syncthreads();
    for (int i = tid; i < NP; i += 256) outp[i] = h[i];
}

// ---------------- merge partials: tiled parallel scan (32 quads x CH chunks / block) ----------
__global__ __launch_bounds__(256) void k_merge(
        unsigned* __restrict__ partial_out, unsigned* __restrict__ partial_in,
        int* __restrict__ cnt_in, float* __restrict__ norm_out,
        float* __restrict__ norm_in, int N, int NP) {
    __shared__ unsigned tile[CH][33];   // 256 x 33 u32 = 33.8KB
    __shared__ unsigned sums[32][9];    // [quad][seg 0..7, total_in at 8]
    int q0 = blockIdx.x * 32;
    int tid = threadIdx.x;
    int qd = tid & 31, k = tid >> 5;

    // ---- pass 1: partial_in -> exclusive prefix + totals ----
    for (int idx = tid; idx < 32 * CH; idx += 256) {
        int c = idx >> 5, q = idx & 31;
        unsigned v = 0;
        if (q0 + q < NP) v = partial_in[(size_t)c * NP + q0 + q];
        tile[c][q] = v;
    }
    __syncthreads();
    unsigned loc = 0;
    #pragma unroll
    for (int i = 0; i < SEG; i++) loc += tile[k * SEG + i][qd];
    sums[qd][k] = loc;
    __syncthreads();
    if (k == 0) {
        unsigned r = 0;
        #pragma unroll
        for (int j = 0; j < 8; j++) { unsigned v = sums[qd][j]; sums[qd][j] = r; r += v; }
        sums[qd][8] = r;   // total in-degree (packed u8 x4)
    }
    __syncthreads();
    unsigned run = sums[qd][k];
    #pragma unroll
    for (int i = 0; i < SEG; i++) {
        unsigned v = tile[k * SEG + i][qd];
        tile[k * SEG + i][qd] = run;
        run += v;
    }
    __syncthreads();
    for (int idx = tid; idx < 32 * CH; idx += 256) {
        int c = idx >> 5, q = idx & 31;
        if (q0 + q < NP) partial_in[(size_t)c * NP + q0 + q] = tile[c][q];
    }
    __syncthreads();

    // ---- pass 2: partial_out totals only ----
    for (int idx = tid; idx < 32 * CH; idx += 256) {
        int c = idx >> 5, q = idx & 31;
        unsigned v = 0;
        if (q0 + q < NP) v = partial_out[(size_t)c * NP + q0 + q];
        tile[c][q] = v;
    }
    __syncthreads();
    unsigned loco = 0;
    #pragma unroll
    for (int i = 0; i < SEG; i++) loco += tile[k * SEG + i][qd];
    sums[qd][k] = loco;
    __syncthreads();
    if (k == 0) {
        unsigned tot = 0;
        #pragma unroll
        for (int j = 0; j < 8; j++) tot += sums[qd][j];
        unsigned rin = sums[qd][8];
        int w = q0 + qd;
        if (w < NP) {
            #pragma unroll
            for (int j = 0; j < 4; j++) {
                int node = w * 4 + j;
                if (node < N) {
                    unsigned di = (rin >> (j * 8)) & 255u;
                    unsigned dd = (tot >> (j * 8)) & 255u;
                    cnt_in[node]   = (int)di;
                    norm_in[node]  = rsqrtf(fmaxf((float)di, 1.0f));
                    norm_out[node] = rsqrtf(fmaxf((float)dd, 1.0f));
                }
            }
        }
    }
}

// ---------------- 2-level exclusive scan of PADDED counts -> row_start ----------------
// rows padded to 16 entries (pads -> zero row N) for the branch-free gather.
__global__ void k_scan_local(const int* __restrict__ cnt, int* __restrict__ excl,
                             int* __restrict__ bsum, int N) {
    __shared__ int s[256];
    int x = threadIdx.x;
    int i = blockIdx.x * 256 + x;
    int v = (i < N) ? ((cnt[i] + 15) & ~15) : 0;
    s[x] = v;
    __syncthreads();
    for (int off = 1; off < 256; off <<= 1) {
        int t = (x >= off) ? s[x - off] : 0;
        __syncthreads();
        s[x] += t;
        __syncthreads();
    }
    if (i < N) excl[i] = s[x] - v;
    if (x == 255) bsum[blockIdx.x] = s[255];
}

// block 0: scan of block sums; blocks 1..128: pack W0,W1 -> bf16 MFMA B-fragment order
__global__ void k_scan_bsum_prep(int* __restrict__ bsum, int* __restrict__ boff, int nb,
                                 const float* __restrict__ W0, const float* __restrict__ W1,
                                 unsigned short* __restrict__ WF0, unsigned short* __restrict__ WF1) {
    if (blockIdx.x == 0) {
        __shared__ int s[256];
        int x = threadIdx.x;
        int v = (x < nb) ? bsum[x] : 0;
        s[x] = v;
        __syncthreads();
        for (int off = 1; off < 256; off <<= 1) {
            int t = (x >= off) ? s[x - off] : 0;
            __syncthreads();
            s[x] += t;
            __syncthreads();
        }
        if (x < nb) boff[x] = s[x] - v;
    } else {
        int t = ((int)blockIdx.x - 1) * 256 + threadIdx.x;  // 0..32767
        const float* __restrict__ W = (t < 16384) ? W0 : W1;
        unsigned short* __restrict__ WF = (t < 16384) ? WF0 : WF1;
        int tt = t & 16383;
        int f = tt >> 9, l = (tt >> 3) & 63, e = tt & 7;
        int n = (f >> 2) * 16 + (l & 15);
        int k = (f & 3) * 32 + (l >> 4) * 8 + e;
        WF[tt] = f2bf(W[k * 128 + n]);
    }
}

// row_start += boff; zero pooled accum g; init csr pads to N; zero the zero-rows of xA/xB
__global__ void k_add_off(int* __restrict__ row_start, const int* __restrict__ boff,
                          float* __restrict__ g, unsigned short* __restrict__ csr,
                          unsigned short* __restrict__ xA, unsigned short* __restrict__ xB,
                          int N, int csrtot) {
    int i = blockIdx.x * blockDim.x + threadIdx.x;
    int stride = gridDim.x * blockDim.x;
    if (i < N) row_start[i] += boff[i >> 8];
    for (int j = i; j < NG * FEAT; j += stride) g[j] = 0.f;
    for (int j = i; j < csrtot; j += stride) csr[j] = (unsigned short)N;
    for (int j = i; j < 256; j += stride) {
        unsigned short* xp = (j < 128) ? xA : xB;
        xp[(size_t)N * FEAT + (j & 127)] = 0;
    }
}

// ---------------- chunked CSR fill (LDS cursors, packed u8, u16 csr) ----------------
__global__ __launch_bounds__(256) void k_fill(
        const int* __restrict__ src, const int* __restrict__ dst,
        const int* __restrict__ row_start, const unsigned* __restrict__ partial_in,
        unsigned short* __restrict__ csr, int N, int E, int NP, int Ec) {
    __shared__ unsigned cur[NPMAX];
    int tid = threadIdx.x;
    int c = blockIdx.x;
    const unsigned* __restrict__ pre = partial_in + (size_t)c * NP;
    for (int i = tid; i < NP; i += 256) cur[i] = pre[i];
    __syncthreads();
    int e0 = c * Ec, e1 = min(E, e0 + Ec);
    for (int e = e0 + tid; e < e1; e += 256) {
        int d = dst[e], s = src[e];
        int sh = (d & 3) * 8;
        unsigned t = atomicAdd(&cur[d >> 2], 1u << sh);
        int off = (int)((t >> sh) & 255u);
        csr[row_start[d] + off] = (unsigned short)s;
    }
}

// ---------------- x0 build (row-major [N+1][128]), full occupancy (no LDS) ----------------
__global__ __launch_bounds__(256) void k_build_x(
        const int* __restrict__ nid, const int* __restrict__ z,
        const float* __restrict__ emb, const float* __restrict__ zt,
        const float* __restrict__ nout, unsigned short* __restrict__ x, int N) {
    int t = blockIdx.x * 256 + threadIdx.x;
    int i = t >> 5, q = t & 31;
    if (i >= N) return;
    float4 v;
    if (q < 16) v = ((const float4*)emb)[(size_t)nid[i] * 16 + q];
    else        v = ((const float4*)zt)[(size_t)z[i] * 16 + (q - 16)];
    float w = nout[i];
    ushort4 u;
    u.x = f2bf(v.x * w); u.y = f2bf(v.y * w);
    u.z = f2bf(v.z * w); u.w = f2bf(v.w * w);
    *(ushort4*)(x + (size_t)i * FEAT + q * 4) = u;
}

// ---------------- branch-free gather: 16 lanes/node, 16B/lane, padded rows ----------------
// Broadcast uint4 loads of 16 u16 csr entries (rows 16-padded to zero row N), bitfield
// extract srcs, 16 independent uint4 x-row loads per iteration (no shfl, no tail).
#define ACC8(u)                                                                  \
    a0 += lo16(u.x); a1 += hi16(u.x); a2 += lo16(u.y); a3 += hi16(u.y);          \
    a4 += lo16(u.z); a5 += hi16(u.z); a6 += lo16(u.w); a7 += hi16(u.w);

#define GATHER_ALL                                                               \
    int base = row_start[node];                                                  \
    int n = cnt_in[node];                                                        \
    const uint4* __restrict__ cp = (const uint4*)(csr + base);                   \
    const uint4* __restrict__ xp = (const uint4*)x;  /* row = 16 uint4 */        \
    for (int j0 = 0; j0 < n; j0 += 16) {                                         \
        uint4 qa = cp[(j0 >> 3)];                                                \
        uint4 qb = cp[(j0 >> 3) + 1];                                            \
        uint4 u0  = xp[(size_t)(qa.x & 0xFFFFu) * 16 + ql];                      \
        uint4 u1  = xp[(size_t)(qa.x >> 16) * 16 + ql];                          \
        uint4 u2  = xp[(size_t)(qa.y & 0xFFFFu) * 16 + ql];                      \
        uint4 u3  = xp[(size_t)(qa.y >> 16) * 16 + ql];                          \
        uint4 u4  = xp[(size_t)(qa.z & 0xFFFFu) * 16 + ql];                      \
        uint4 u5  = xp[(size_t)(qa.z >> 16) * 16 + ql];                          \
        uint4 u6  = xp[(size_t)(qa.w & 0xFFFFu) * 16 + ql];                      \
        uint4 u7  = xp[(size_t)(qa.w >> 16) * 16 + ql];                          \
        uint4 u8  = xp[(size_t)(qb.x & 0xFFFFu) * 16 + ql];                      \
        uint4 u9  = xp[(size_t)(qb.x >> 16) * 16 + ql];                          \
        uint4 u10 = xp[(size_t)(qb.y & 0xFFFFu) * 16 + ql];                      \
        uint4 u11 = xp[(size_t)(qb.y >> 16) * 16 + ql];                          \
        uint4 u12 = xp[(size_t)(qb.z & 0xFFFFu) * 16 + ql];                      \
        uint4 u13 = xp[(size_t)(qb.z >> 16) * 16 + ql];                          \
        uint4 u14 = xp[(size_t)(qb.w & 0xFFFFu) * 16 + ql];                      \
        uint4 u15 = xp[(size_t)(qb.w >> 16) * 16 + ql];                          \
        ACC8(u0)  ACC8(u1)  ACC8(u2)  ACC8(u3)                                   \
        ACC8(u4)  ACC8(u5)  ACC8(u6)  ACC8(u7)                                   \
        ACC8(u8)  ACC8(u9)  ACC8(u10) ACC8(u11)                                  \
        ACC8(u12) ACC8(u13) ACC8(u14) ACC8(u15)                                  \
    }

// ---------------- fused gather + MFMA GEMM, 16 nodes/block ----------------
__global__ __launch_bounds__(256) void k_gather_gemm(
        const unsigned short* __restrict__ x, const float* __restrict__ nin,
        const unsigned short* __restrict__ csr, const int* __restrict__ row_start,
        const int* __restrict__ cnt_in, const unsigned short* __restrict__ WF,
        const float* __restrict__ bias, const float* __restrict__ nout,
        unsigned short* __restrict__ y, int N) {
    __shared__ unsigned short As[16 * LDW];  // 4.3KB
    int tid = threadIdx.x;
    int nb = blockIdx.x * 16;
    int ql = tid & 15;
    int nl = tid >> 4;
    int node = nb + nl;

    float a0 = 0.f, a1 = 0.f, a2 = 0.f, a3 = 0.f;
    float a4 = 0.f, a5 = 0.f, a6 = 0.f, a7 = 0.f;
    if (node < N) {
        GATHER_ALL
        float ni = nin[node];
        a0 *= ni; a1 *= ni; a2 *= ni; a3 *= ni;
        a4 *= ni; a5 *= ni; a6 *= ni; a7 *= ni;
    }
    uint4 o;
    o.x = (unsigned)f2bf(a0) | ((unsigned)f2bf(a1) << 16);
    o.y = (unsigned)f2bf(a2) | ((unsigned)f2bf(a3) << 16);
    o.z = (unsigned)f2bf(a4) | ((unsigned)f2bf(a5) << 16);
    o.w = (unsigned)f2bf(a6) | ((unsigned)f2bf(a7) << 16);
    *(uint4*)(As + nl * LDW + ql * 8) = o;
    __syncthreads();

    int lane = tid & 63;
    int wv = tid >> 6;
    int c = lane & 15, q = lane >> 4;

    // shared 16-row A-fragments (identical across waves: LDS broadcast)
    const unsigned short* ap = As + c * LDW + q * 8;
    bf16x8 fa0 = *(const bf16x8*)(ap);
    bf16x8 fa1 = *(const bf16x8*)(ap + 32);
    bf16x8 fa2 = *(const bf16x8*)(ap + 64);
    bf16x8 fa3 = *(const bf16x8*)(ap + 96);
    const bf16x8* __restrict__ wf = (const bf16x8*)WF;
    __syncthreads();  // A-frags in regs; safe to overwrite As with outputs

    #pragma unroll
    for (int t = 0; t < 2; t++) {
        int nt = wv * 2 + t;
        bf16x8 fb0 = wf[(nt * 4 + 0) * 64 + lane];
        bf16x8 fb1 = wf[(nt * 4 + 1) * 64 + lane];
        bf16x8 fb2 = wf[(nt * 4 + 2) * 64 + lane];
        bf16x8 fb3 = wf[(nt * 4 + 3) * 64 + lane];
        float bb = bias[nt * 16 + c];
        f32x4 acc = {bb, bb, bb, bb};
        acc = __builtin_amdgcn_mfma_f32_16x16x32_bf16(fa0, fb0, acc, 0, 0, 0);
        acc = __builtin_amdgcn_mfma_f32_16x16x32_bf16(fa1, fb1, acc, 0, 0, 0);
        acc = __builtin_amdgcn_mfma_f32_16x16x32_bf16(fa2, fb2, acc, 0, 0, 0);
        acc = __builtin_amdgcn_mfma_f32_16x16x32_bf16(fa3, fb3, acc, 0, 0, 0);
        #pragma unroll
        for (int rr = 0; rr < 4; rr++) {
            int row = q * 4 + rr;
            float s = nout[min(nb + row, N - 1)];
            As[row * LDW + nt * 16 + c] = f2bf(fmaxf(acc[rr], 0.f) * s);
        }
    }
    __syncthreads();

    // coalesced store: 16 rows x 128 u16
    {
        int row = tid >> 4, seg = tid & 15;
        int nd = nb + row;
        if (nd < N) {
            const ushort4* p = (const ushort4*)(As + row * LDW + seg * 8);
            ushort4* d = (ushort4*)(y + (size_t)nd * FEAT + seg * 8);
            d[0] = p[0]; d[1] = p[1];
        }
    }
}

// ---------------- fused layer-2 gather + SumPool ----------------
__global__ __launch_bounds__(256) void k_gather_pool(
        const unsigned short* __restrict__ x, const float* __restrict__ nin,
        const unsigned short* __restrict__ csr, const int* __restrict__ row_start,
        const int* __restrict__ cnt_in, const int* __restrict__ gid,
        float* __restrict__ g, int N) {
    __shared__ __align__(16) float gl[16][132];  // per-node partials, +4 pad
    __shared__ int slots[16];
    int tid = threadIdx.x;
    int nb = blockIdx.x * 16;
    int ql = tid & 15;
    int nl = tid >> 4;
    int node = nb + nl;

    float a0 = 0.f, a1 = 0.f, a2 = 0.f, a3 = 0.f;
    float a4 = 0.f, a5 = 0.f, a6 = 0.f, a7 = 0.f;
    int slot = -1;
    if (node < N) {
        GATHER_ALL
        float ni = nin[node];
        a0 *= ni; a1 *= ni; a2 *= ni; a3 *= ni;
        a4 *= ni; a5 *= ni; a6 *= ni; a7 *= ni;
        slot = gid[node];
    }
    float4* row = (float4*)&gl[nl][ql * 8];
    row[0] = make_float4(a0, a1, a2, a3);
    row[1] = make_float4(a4, a5, a6, a7);
    if (ql == 0) slots[nl] = slot;
    __syncthreads();

    int h = tid >> 7;       // 0/1: nodes 0-7 / 8-15
    int j = tid & 127;
    int prev = -1;
    float acc = 0.f;
    #pragma unroll
    for (int i = h * 8; i < h * 8 + 8; i++) {
        int s = slots[i];
        if (s != prev) {
            if (prev >= 0) atomicAdd(&g[(size_t)prev * FEAT + j], acc);
            acc = 0.f;
            prev = s;
        }
        acc += gl[i][j];
    }
    if (prev >= 0) atomicAdd(&g[(size_t)prev * FEAT + j], acc);
}

// ---------------- head: ys = g@W2 + cnt*b2 ; out = relu(ys@l1W+l1b)@l2W+l2b ----------------
__global__ __launch_bounds__(256) void k_head(
        const float* __restrict__ g, const int* __restrict__ gid,
        const float* __restrict__ W2, const float* __restrict__ b2,
        const float* __restrict__ l1W, const float* __restrict__ l1b,
        const float* __restrict__ l2W, const float* __restrict__ l2b,
        float* __restrict__ out, int N) {
    __shared__ float gs[128];
    __shared__ float ys[128];
    __shared__ float hs[128];
    int gi = blockIdx.x, tid = threadIdx.x;

    int lo = 0, hi = N;
    while (lo < hi) { int m = (lo + hi) >> 1; if (gid[m] < gi) lo = m + 1; else hi = m; }
    int s0 = lo;
    lo = 0; hi = N;
    while (lo < hi) { int m = (lo + hi) >> 1; if (gid[m] < gi + 1) lo = m + 1; else hi = m; }
    float cnt = (float)(lo - s0);

    if (tid < 128) gs[tid] = g[(size_t)gi * FEAT + tid];
    __syncthreads();
    if (tid < 128) {
        float a = cnt * b2[tid];
        for (int k = 0; k < 128; k++) a += gs[k] * W2[(size_t)k * 128 + tid];
        ys[tid] = a;
    }
    __syncthreads();
    if (tid < 128) {
        float a = l1b[tid];
        for (int k = 0; k < 128; k++) a += ys[k] * l1W[(size_t)k * 128 + tid];
        hs[tid] = fmaxf(a, 0.f);
    }
    __syncthreads();
    if (tid < 200) {
        float a = l2b[tid];
        for (int k = 0; k < 128; k++) a += hs[k] * l2W[(size_t)k * 200 + tid];
        out[(size_t)gi * 200 + tid] = a;
    }
}

extern "C" void kernel_launch(void* const* d_in, const int* in_sizes, int n_in,
                              void* d_out, int out_size, void* d_ws, size_t ws_size,
                              hipStream_t stream) {
    const int*   nid = (const int*)d_in[0];
    const int*   z   = (const int*)d_in[1];
    const int*   src = (const int*)d_in[2];
    const int*   dst = (const int*)d_in[3];
    const int*   gid = (const int*)d_in[4];
    const float* emb = (const float*)d_in[5];
    const float* zt  = (const float*)d_in[6];
    const float* W0  = (const float*)d_in[7];
    const float* b0  = (const float*)d_in[8];
    const float* W1  = (const float*)d_in[9];
    const float* b1  = (const float*)d_in[10];
    const float* W2  = (const float*)d_in[11];
    const float* b2  = (const float*)d_in[12];
    const float* l1W = (const float*)d_in[13];
    const float* l1b = (const float*)d_in[14];
    const float* l2W = (const float*)d_in[15];
    const float* l2b = (const float*)d_in[16];
    float* out = (float*)d_out;

    const int N = in_sizes[0];
    const int E = in_sizes[2];
    const int NB = (N + 255) / 256;     // scan blocks (<=256 required)
    const int NP = (N + 3) / 4;         // node-quads (<= NPMAX)
    const int Ec = (E + CH - 1) / CH;   // edges per chunk
    const int CSRTOT = E + 16 * N + 64; // padded csr capacity (u16)
    const size_t XSZ = (size_t)(N + 1) * FEAT;  // x rows + zero row N

    // ---- workspace ----
    size_t NA = (size_t)((N + 63) & ~63);
    float* norm_out = (float*)d_ws;                      // NA
    float* norm_in  = norm_out + NA;                     // NA
    float* g        = norm_in + NA;                      // NG*FEAT fp32 pooled accum
    unsigned short* xA  = (unsigned short*)(g + (size_t)NG * FEAT);  // XSZ
    unsigned short* xB  = xA + XSZ;                      // XSZ
    unsigned short* WF0 = xB + XSZ;                      // 128*128 bf16 (fragment order)
    unsigned short* WF1 = WF0 + 128 * 128;               // 128*128 bf16
    int* cnt_in    = (int*)(WF1 + 128 * 128);            // NA
    int* row_start = cnt_in + NA;                        // NA
    int* bsum      = row_start + NA;                     // 256
    int* boff      = bsum + 256;                         // 256
    unsigned* partial_out = (unsigned*)(boff + 256);     // CH*NP
    unsigned* partial_in  = partial_out + (size_t)CH * NP; // CH*NP
    unsigned short* csr = (unsigned short*)(partial_in + (size_t)CH * NP); // CSRTOT u16

    // ---- atomic-free CSR build + norms + W fragment packs ----
    k_hist<<<2 * CH, 256, 0, stream>>>(src, dst, partial_out, partial_in, E, NP, Ec);
    k_merge<<<(NP + 31) / 32, 256, 0, stream>>>(partial_out, partial_in, cnt_in,
                                                norm_out, norm_in, N, NP);
    k_scan_local<<<NB, 256, 0, stream>>>(cnt_in, row_start, bsum, N);
    k_scan_bsum_prep<<<1 + 128, 256, 0, stream>>>(bsum, boff, NB, W0, W1, WF0, WF1);
    k_add_off<<<NB, 256, 0, stream>>>(row_start, boff, g, csr, xA, xB, N, CSRTOT);
    k_build_x<<<(N * 32 + 255) / 256, 256, 0, stream>>>(nid, z, emb, zt, norm_out, xA, N);
    k_fill<<<CH, 256, 0, stream>>>(src, dst, row_start, partial_in, csr, N, E, NP, Ec);

    int gg_blocks = (N + 15) / 16;

    // layer 0: xA -> xB (fused gather+GEMM, 16 nodes/block)
    k_gather_gemm<<<gg_blocks, 256, 0, stream>>>(xA, norm_in, csr, row_start, cnt_in,
                                                 WF0, b0, norm_out, xB, N);
    // layer 1: xB -> xA
    k_gather_gemm<<<gg_blocks, 256, 0, stream>>>(xB, norm_in, csr, row_start, cnt_in,
                                                 WF1, b1, norm_out, xA, N);
    // layer 2: gather fused with SumPool (GEMM commuted past pool via linearity)
    k_gather_pool<<<gg_blocks, 256, 0, stream>>>(xA, norm_in, csr, row_start, cnt_in,
                                                 gid, g, N);

    // tiny per-graph MLP head
    k_head<<<NG, 256, 0, stream>>>(g, gid, W2, b2, l1W, l1b, l2W, l2b, out, N);
}

// Round 8
// 283.896 us; speedup vs baseline: 1.0682x; 1.0042x over previous
//
#include <hip/hip_runtime.h>
#include <hip/hip_bf16.h>

// SEAL GCN: 3x GraphConv(norm=both) -> SumPool(graph_id sorted) -> MLP(128->128 relu ->200)
// N=50000, E=800000, feat=128, 512 graphs.
// R18: revert gather core to R14's measured-best (8-deep shfl, exact counts, 16B/lane);
//      attack the ~150us prepass: fuse k_build_x into k_merge (norms stashed in LDS),
//      delete k_add_off (excl+boff computed inline in fill/gathers), fold g-zero into
//      k_scan_bsum_prep. 11 -> 9 launches. CH=128 (half of R17's partials traffic).

#define FEAT 128
#define NG 512
#define CH 128       // edge chunks for hist/fill
#define SEG (CH / 8) // chunks per scan segment in k_merge
#define NPMAX 12544  // max node-quads (N<=50176); 50KB static LDS
#define LDW 136      // LDS row stride in ushorts (bf16): 2-way-free banks for b128

typedef __attribute__((ext_vector_type(8))) short bf16x8;
typedef __attribute__((ext_vector_type(4))) float f32x4;

__device__ __forceinline__ unsigned short f2bf(float f) {
    unsigned int u = __float_as_uint(f);
    return (unsigned short)((u + 0x7FFFu + ((u >> 16) & 1u)) >> 16);  // RNE
}
__device__ __forceinline__ float lo16(unsigned u) { return __uint_as_float(u << 16); }
__device__ __forceinline__ float hi16(unsigned u) { return __uint_as_float(u & 0xFFFF0000u); }

// ---------------- chunked full-range histogram, packed u8, zero global atomics ----------------
__global__ __launch_bounds__(256) void k_hist(
        const int* __restrict__ src, const int* __restrict__ dst,
        unsigned* __restrict__ partial_out, unsigned* __restrict__ partial_in,
        int E, int NP, int Ec) {
    __shared__ unsigned h[NPMAX];
    int tid = threadIdx.x;
    int b = blockIdx.x;
    int c = b & (CH - 1);
    const int* __restrict__ arr = (b < CH) ? src : dst;
    unsigned* __restrict__ outp = ((b < CH) ? partial_out : partial_in) + (size_t)c * NP;
    for (int i = tid; i < NP; i += 256) h[i] = 0;
    __syncthreads();
    int e0 = c * Ec, e1 = min(E, e0 + Ec);
    for (int e = e0 + tid; e < e1; e += 256) {
        int v = arr[e];
        atomicAdd(&h[v >> 2], 1u << ((v & 3) * 8));
    }
    __syncthreads();
    for (int i = tid; i < NP; i += 256) outp[i] = h[i];
}

// ---------------- merge partials (tiled parallel scan) + fused x0 build ----------------
// Per block: 32 quads x CH chunks scan -> prefix/totals/norms; then build x0 rows for
// this block's 128 nodes using LDS-stashed norm_out (no separate k_build_x pass).
__global__ __launch_bounds__(256) void k_merge(
        unsigned* __restrict__ partial_out, unsigned* __restrict__ partial_in,
        int* __restrict__ cnt_in, float* __restrict__ norm_out,
        float* __restrict__ norm_in,
        const int* __restrict__ nid, const int* __restrict__ z,
        const float* __restrict__ emb, const float* __restrict__ zt,
        unsigned short* __restrict__ x, int N, int NP) {
    __shared__ unsigned tile[CH][33];   // 128 x 33 u32 = 16.9KB
    __shared__ unsigned sums[32][9];    // [quad][seg 0..7, total_in at 8]
    __shared__ float nout_l[128];
    int q0 = blockIdx.x * 32;
    int tid = threadIdx.x;
    int qd = tid & 31, k = tid >> 5;

    // ---- pass 1: partial_in -> exclusive prefix + totals ----
    for (int idx = tid; idx < 32 * CH; idx += 256) {
        int c = idx >> 5, q = idx & 31;
        unsigned v = 0;
        if (q0 + q < NP) v = partial_in[(size_t)c * NP + q0 + q];
        tile[c][q] = v;
    }
    __syncthreads();
    unsigned loc = 0;
    #pragma unroll
    for (int i = 0; i < SEG; i++) loc += tile[k * SEG + i][qd];
    sums[qd][k] = loc;
    __syncthreads();
    if (k == 0) {
        unsigned r = 0;
        #pragma unroll
        for (int j = 0; j < 8; j++) { unsigned v = sums[qd][j]; sums[qd][j] = r; r += v; }
        sums[qd][8] = r;   // total in-degree (packed u8 x4)
    }
    __syncthreads();
    unsigned run = sums[qd][k];
    #pragma unroll
    for (int i = 0; i < SEG; i++) {
        unsigned v = tile[k * SEG + i][qd];
        tile[k * SEG + i][qd] = run;
        run += v;
    }
    __syncthreads();
    for (int idx = tid; idx < 32 * CH; idx += 256) {
        int c = idx >> 5, q = idx & 31;
        if (q0 + q < NP) partial_in[(size_t)c * NP + q0 + q] = tile[c][q];
    }
    __syncthreads();

    // ---- pass 2: partial_out totals; norms; stash norm_out in LDS ----
    for (int idx = tid; idx < 32 * CH; idx += 256) {
        int c = idx >> 5, q = idx & 31;
        unsigned v = 0;
        if (q0 + q < NP) v = partial_out[(size_t)c * NP + q0 + q];
        tile[c][q] = v;
    }
    __syncthreads();
    unsigned loco = 0;
    #pragma unroll
    for (int i = 0; i < SEG; i++) loco += tile[k * SEG + i][qd];
    sums[qd][k] = loco;   // safe: prefix values consumed; [8] untouched
    __syncthreads();
    if (k == 0) {
        unsigned tot = 0;
        #pragma unroll
        for (int j = 0; j < 8; j++) tot += sums[qd][j];
        unsigned rin = sums[qd][8];
        int w = q0 + qd;
        if (w < NP) {
            #pragma unroll
            for (int j = 0; j < 4; j++) {
                int node = w * 4 + j;
                if (node < N) {
                    unsigned di = (rin >> (j * 8)) & 255u;
                    unsigned dd = (tot >> (j * 8)) & 255u;
                    cnt_in[node]   = (int)di;
                    norm_in[node]  = rsqrtf(fmaxf((float)di, 1.0f));
                    float no = rsqrtf(fmaxf((float)dd, 1.0f));
                    norm_out[node] = no;
                    nout_l[qd * 4 + j] = no;
                }
            }
        }
    }
    __syncthreads();

    // ---- fused x0 build for nodes [q0*4, q0*4+128) ----
    int nbase = q0 * 4;
    for (int t = tid; t < 128 * 32; t += 256) {
        int nl = t >> 5, q = t & 31;
        int node = nbase + nl;
        if (node < N) {
            float4 v;
            if (q < 16) v = ((const float4*)emb)[(size_t)nid[node] * 16 + q];
            else        v = ((const float4*)zt)[(size_t)z[node] * 16 + (q - 16)];
            float w = nout_l[nl];
            ushort4 u;
            u.x = f2bf(v.x * w); u.y = f2bf(v.y * w);
            u.z = f2bf(v.z * w); u.w = f2bf(v.w * w);
            *(ushort4*)(x + (size_t)node * FEAT + q * 4) = u;
        }
    }
}

// ---------------- 2-level exclusive scan of cnt_in -> excl (block-local) ----------------
__global__ void k_scan_local(const int* __restrict__ cnt, int* __restrict__ excl,
                             int* __restrict__ bsum, int N) {
    __shared__ int s[256];
    int x = threadIdx.x;
    int i = blockIdx.x * 256 + x;
    int v = (i < N) ? cnt[i] : 0;
    s[x] = v;
    __syncthreads();
    for (int off = 1; off < 256; off <<= 1) {
        int t = (x >= off) ? s[x - off] : 0;
        __syncthreads();
        s[x] += t;
        __syncthreads();
    }
    if (i < N) excl[i] = s[x] - v;
    if (x == 255) bsum[blockIdx.x] = s[255];
}

// block 0: scan of block sums; blocks 1..128: pack W0,W1 -> MFMA B-fragment order;
// blocks 129..160: zero pooled accum g.
__global__ void k_scan_bsum_prep(int* __restrict__ bsum, int* __restrict__ boff, int nb,
                                 const float* __restrict__ W0, const float* __restrict__ W1,
                                 unsigned short* __restrict__ WF0, unsigned short* __restrict__ WF1,
                                 float* __restrict__ g) {
    if (blockIdx.x == 0) {
        __shared__ int s[256];
        int x = threadIdx.x;
        int v = (x < nb) ? bsum[x] : 0;
        s[x] = v;
        __syncthreads();
        for (int off = 1; off < 256; off <<= 1) {
            int t = (x >= off) ? s[x - off] : 0;
            __syncthreads();
            s[x] += t;
            __syncthreads();
        }
        if (x < nb) boff[x] = s[x] - v;
    } else if ((int)blockIdx.x <= 128) {
        int t = ((int)blockIdx.x - 1) * 256 + threadIdx.x;  // 0..32767
        const float* __restrict__ W = (t < 16384) ? W0 : W1;
        unsigned short* __restrict__ WF = (t < 16384) ? WF0 : WF1;
        int tt = t & 16383;
        int f = tt >> 9, l = (tt >> 3) & 63, e = tt & 7;
        int n = (f >> 2) * 16 + (l & 15);
        int k = (f & 3) * 32 + (l >> 4) * 8 + e;
        WF[tt] = f2bf(W[k * 128 + n]);
    } else {
        int j0 = ((int)blockIdx.x - 129) * 2048 + threadIdx.x * 8;  // NG*FEAT = 65536
        #pragma unroll
        for (int j = 0; j < 8; j++) g[j0 + j] = 0.f;
    }
}

// ---------------- chunked CSR fill (LDS cursors, packed u8, u16 csr) ----------------
__global__ __launch_bounds__(256) void k_fill(
        const int* __restrict__ src, const int* __restrict__ dst,
        const int* __restrict__ excl, const int* __restrict__ boff,
        const unsigned* __restrict__ partial_in,
        unsigned short* __restrict__ csr, int N, int E, int NP, int Ec) {
    __shared__ unsigned cur[NPMAX];
    int tid = threadIdx.x;
    int c = blockIdx.x;
    const unsigned* __restrict__ pre = partial_in + (size_t)c * NP;
    for (int i = tid; i < NP; i += 256) cur[i] = pre[i];
    __syncthreads();
    int e0 = c * Ec, e1 = min(E, e0 + Ec);
    for (int e = e0 + tid; e < e1; e += 256) {
        int d = dst[e], s = src[e];
        int sh = (d & 3) * 8;
        unsigned t = atomicAdd(&cur[d >> 2], 1u << sh);
        int off = (int)((t >> sh) & 255u);
        csr[excl[d] + boff[d >> 8] + off] = (unsigned short)s;
    }
}

// ---------------- gather core: b128 loads, 16 lanes/node, 8-deep ILP (R14 best) ----------------
#define ACC8(u)                                                                  \
    a0 += lo16(u.x); a1 += hi16(u.x); a2 += lo16(u.y); a3 += hi16(u.y);          \
    a4 += lo16(u.z); a5 += hi16(u.z); a6 += lo16(u.w); a7 += hi16(u.w);

#define GATHER_LOOP                                                              \
    {                                                                            \
        int base = row_start[node] + boff[node >> 8];                            \
        int n = cnt_in[node];                                                    \
        const uint4* xp = (const uint4*)x;  /* row = 16 uint4 */                 \
        for (int j0 = 0; j0 < n; j0 += 16) {                                     \
            int rem = n - j0;                                                    \
            int m = rem < 16 ? rem : 16;                                         \
            int e = (int)csr[base + j0 + (ql < m ? ql : 0)];                     \
            int j = 0;                                                           \
            for (; j + 8 <= m; j += 8) {                                         \
                int s0 = __shfl(e, j + 0, 16), s1 = __shfl(e, j + 1, 16);        \
                int s2 = __shfl(e, j + 2, 16), s3 = __shfl(e, j + 3, 16);        \
                int s4 = __shfl(e, j + 4, 16), s5 = __shfl(e, j + 5, 16);        \
                int s6 = __shfl(e, j + 6, 16), s7 = __shfl(e, j + 7, 16);        \
                uint4 u0 = xp[(size_t)s0 * 16 + ql];                             \
                uint4 u1 = xp[(size_t)s1 * 16 + ql];                             \
                uint4 u2 = xp[(size_t)s2 * 16 + ql];                             \
                uint4 u3 = xp[(size_t)s3 * 16 + ql];                             \
                uint4 u4 = xp[(size_t)s4 * 16 + ql];                             \
                uint4 u5 = xp[(size_t)s5 * 16 + ql];                             \
                uint4 u6 = xp[(size_t)s6 * 16 + ql];                             \
                uint4 u7 = xp[(size_t)s7 * 16 + ql];                             \
                ACC8(u0) ACC8(u1) ACC8(u2) ACC8(u3)                              \
                ACC8(u4) ACC8(u5) ACC8(u6) ACC8(u7)                              \
            }                                                                    \
            for (; j + 4 <= m; j += 4) {                                         \
                int s0 = __shfl(e, j + 0, 16), s1 = __shfl(e, j + 1, 16);        \
                int s2 = __shfl(e, j + 2, 16), s3 = __shfl(e, j + 3, 16);        \
                uint4 u0 = xp[(size_t)s0 * 16 + ql];                             \
                uint4 u1 = xp[(size_t)s1 * 16 + ql];                             \
                uint4 u2 = xp[(size_t)s2 * 16 + ql];                             \
                uint4 u3 = xp[(size_t)s3 * 16 + ql];                             \
                ACC8(u0) ACC8(u1) ACC8(u2) ACC8(u3)                              \
            }                                                                    \
            for (; j < m; j++) {                                                 \
                int s = __shfl(e, j, 16);                                        \
                uint4 u = xp[(size_t)s * 16 + ql];                               \
                ACC8(u)                                                          \
            }                                                                    \
        }                                                                        \
    }

// ---------------- fused gather + MFMA GEMM, 16 nodes/block ----------------
__global__ __launch_bounds__(256, 8) void k_gather_gemm(
        const unsigned short* __restrict__ x, const float* __restrict__ nin,
        const unsigned short* __restrict__ csr, const int* __restrict__ row_start,
        const int* __restrict__ boff, const int* __restrict__ cnt_in,
        const unsigned short* __restrict__ WF,
        const float* __restrict__ bias, const float* __restrict__ nout,
        unsigned short* __restrict__ y, int N) {
    __shared__ unsigned short As[16 * LDW];  // 4.3KB
    int tid = threadIdx.x;
    int nb = blockIdx.x * 16;
    int ql = tid & 15;
    int nl = tid >> 4;
    int node = nb + nl;

    float a0 = 0.f, a1 = 0.f, a2 = 0.f, a3 = 0.f;
    float a4 = 0.f, a5 = 0.f, a6 = 0.f, a7 = 0.f;
    if (node < N) {
        GATHER_LOOP
        float ni = nin[node];
        a0 *= ni; a1 *= ni; a2 *= ni; a3 *= ni;
        a4 *= ni; a5 *= ni; a6 *= ni; a7 *= ni;
    }
    uint4 o;
    o.x = (unsigned)f2bf(a0) | ((unsigned)f2bf(a1) << 16);
    o.y = (unsigned)f2bf(a2) | ((unsigned)f2bf(a3) << 16);
    o.z = (unsigned)f2bf(a4) | ((unsigned)f2bf(a5) << 16);
    o.w = (unsigned)f2bf(a6) | ((unsigned)f2bf(a7) << 16);
    *(uint4*)(As + nl * LDW + ql * 8) = o;
    __syncthreads();

    int lane = tid & 63;
    int wv = tid >> 6;
    int c = lane & 15, q = lane >> 4;

    // shared 16-row A-fragments (identical across waves: LDS broadcast)
    const unsigned short* ap = As + c * LDW + q * 8;
    bf16x8 fa0 = *(const bf16x8*)(ap);
    bf16x8 fa1 = *(const bf16x8*)(ap + 32);
    bf16x8 fa2 = *(const bf16x8*)(ap + 64);
    bf16x8 fa3 = *(const bf16x8*)(ap + 96);
    const bf16x8* __restrict__ wf = (const bf16x8*)WF;
    __syncthreads();  // A-frags in regs; safe to overwrite As with outputs

    #pragma unroll
    for (int t = 0; t < 2; t++) {
        int nt = wv * 2 + t;
        bf16x8 fb0 = wf[(nt * 4 + 0) * 64 + lane];
        bf16x8 fb1 = wf[(nt * 4 + 1) * 64 + lane];
        bf16x8 fb2 = wf[(nt * 4 + 2) * 64 + lane];
        bf16x8 fb3 = wf[(nt * 4 + 3) * 64 + lane];
        float bb = bias[nt * 16 + c];
        f32x4 acc = {bb, bb, bb, bb};
        acc = __builtin_amdgcn_mfma_f32_16x16x32_bf16(fa0, fb0, acc, 0, 0, 0);
        acc = __builtin_amdgcn_mfma_f32_16x16x32_bf16(fa1, fb1, acc, 0, 0, 0);
        acc = __builtin_amdgcn_mfma_f32_16x16x32_bf16(fa2, fb2, acc, 0, 0, 0);
        acc = __builtin_amdgcn_mfma_f32_16x16x32_bf16(fa3, fb3, acc, 0, 0, 0);
        #pragma unroll
        for (int rr = 0; rr < 4; rr++) {
            int row = q * 4 + rr;
            float s = nout[min(nb + row, N - 1)];
            As[row * LDW + nt * 16 + c] = f2bf(fmaxf(acc[rr], 0.f) * s);
        }
    }
    __syncthreads();

    // coalesced store: 16 rows x 128 u16
    {
        int row = tid >> 4, seg = tid & 15;
        int nd = nb + row;
        if (nd < N) {
            const ushort4* p = (const ushort4*)(As + row * LDW + seg * 8);
            ushort4* d = (ushort4*)(y + (size_t)nd * FEAT + seg * 8);
            d[0] = p[0]; d[1] = p[1];
        }
    }
}

// ---------------- fused layer-2 gather + SumPool ----------------
__global__ __launch_bounds__(256, 8) void k_gather_pool(
        const unsigned short* __restrict__ x, const float* __restrict__ nin,
        const unsigned short* __restrict__ csr, const int* __restrict__ row_start,
        const int* __restrict__ boff, const int* __restrict__ cnt_in,
        const int* __restrict__ gid, float* __restrict__ g, int N) {
    __shared__ __align__(16) float gl[16][132];  // per-node partials, +4 pad
    __shared__ int slots[16];
    int tid = threadIdx.x;
    int nb = blockIdx.x * 16;
    int ql = tid & 15;
    int nl = tid >> 4;
    int node = nb + nl;

    float a0 = 0.f, a1 = 0.f, a2 = 0.f, a3 = 0.f;
    float a4 = 0.f, a5 = 0.f, a6 = 0.f, a7 = 0.f;
    int slot = -1;
    if (node < N) {
        GATHER_LOOP
        float ni = nin[node];
        a0 *= ni; a1 *= ni; a2 *= ni; a3 *= ni;
        a4 *= ni; a5 *= ni; a6 *= ni; a7 *= ni;
        slot = gid[node];
    }
    float4* row = (float4*)&gl[nl][ql * 8];
    row[0] = make_float4(a0, a1, a2, a3);
    row[1] = make_float4(a4, a5, a6, a7);
    if (ql == 0) slots[nl] = slot;
    __syncthreads();

    int h = tid >> 7;       // 0/1: nodes 0-7 / 8-15
    int j = tid & 127;
    int prev = -1;
    float acc = 0.f;
    #pragma unroll
    for (int i = h * 8; i < h * 8 + 8; i++) {
        int s = slots[i];
        if (s != prev) {
            if (prev >= 0) atomicAdd(&g[(size_t)prev * FEAT + j], acc);
            acc = 0.f;
            prev = s;
        }
        acc += gl[i][j];
    }
    if (prev >= 0) atomicAdd(&g[(size_t)prev * FEAT + j], acc);
}

// ---------------- head: ys = g@W2 + cnt*b2 ; out = relu(ys@l1W+l1b)@l2W+l2b ----------------
__global__ __launch_bounds__(256) void k_head(
        const float* __restrict__ g, const int* __restrict__ gid,
        const float* __restrict__ W2, const float* __restrict__ b2,
        const float* __restrict__ l1W, const float* __restrict__ l1b,
        const float* __restrict__ l2W, const float* __restrict__ l2b,
        float* __restrict__ out, int N) {
    __shared__ float gs[128];
    __shared__ float ys[128];
    __shared__ float hs[128];
    int gi = blockIdx.x, tid = threadIdx.x;

    int lo = 0, hi = N;
    while (lo < hi) { int m = (lo + hi) >> 1; if (gid[m] < gi) lo = m + 1; else hi = m; }
    int s0 = lo;
    lo = 0; hi = N;
    while (lo < hi) { int m = (lo + hi) >> 1; if (gid[m] < gi + 1) lo = m + 1; else hi = m; }
    float cnt = (float)(lo - s0);

    if (tid < 128) gs[tid] = g[(size_t)gi * FEAT + tid];
    __syncthreads();
    if (tid < 128) {
        float a = cnt * b2[tid];
        for (int k = 0; k < 128; k++) a += gs[k] * W2[(size_t)k * 128 + tid];
        ys[tid] = a;
    }
    __syncthreads();
    if (tid < 128) {
        float a = l1b[tid];
        for (int k = 0; k < 128; k++) a += ys[k] * l1W[(size_t)k * 128 + tid];
        hs[tid] = fmaxf(a, 0.f);
    }
    __syncthreads();
    if (tid < 200) {
        float a = l2b[tid];
        for (int k = 0; k < 128; k++) a += hs[k] * l2W[(size_t)k * 200 + tid];
        out[(size_t)gi * 200 + tid] = a;
    }
}

extern "C" void kernel_launch(void* const* d_in, const int* in_sizes, int n_in,
                              void* d_out, int out_size, void* d_ws, size_t ws_size,
                              hipStream_t stream) {
    const int*   nid = (const int*)d_in[0];
    const int*   z   = (const int*)d_in[1];
    const int*   src = (const int*)d_in[2];
    const int*   dst = (const int*)d_in[3];
    const int*   gid = (const int*)d_in[4];
    const float* emb = (const float*)d_in[5];
    const float* zt  = (const float*)d_in[6];
    const float* W0  = (const float*)d_in[7];
    const float* b0  = (const float*)d_in[8];
    const float* W1  = (const float*)d_in[9];
    const float* b1  = (const float*)d_in[10];
    const float* W2  = (const float*)d_in[11];
    const float* b2  = (const float*)d_in[12];
    const float* l1W = (const float*)d_in[13];
    const float* l1b = (const float*)d_in[14];
    const float* l2W = (const float*)d_in[15];
    const float* l2b = (const float*)d_in[16];
    float* out = (float*)d_out;

    const int N = in_sizes[0];
    const int E = in_sizes[2];
    const int NB = (N + 255) / 256;     // scan blocks (<=256 required)
    const int NP = (N + 3) / 4;         // node-quads (<= NPMAX)
    const int Ec = (E + CH - 1) / CH;   // edges per chunk

    // ---- workspace ----
    size_t NA = (size_t)((N + 63) & ~63);
    float* norm_out = (float*)d_ws;                      // NA
    float* norm_in  = norm_out + NA;                     // NA
    float* g        = norm_in + NA;                      // NG*FEAT fp32 pooled accum
    unsigned short* xA  = (unsigned short*)(g + (size_t)NG * FEAT);  // N*128 bf16
    unsigned short* xB  = xA + (size_t)N * FEAT;         // N*128 bf16
    unsigned short* WF0 = xB + (size_t)N * FEAT;         // 128*128 bf16 (fragment order)
    unsigned short* WF1 = WF0 + 128 * 128;               // 128*128 bf16
    int* cnt_in    = (int*)(WF1 + 128 * 128);            // NA
    int* excl      = cnt_in + NA;                        // NA (block-local scan)
    int* bsum      = excl + NA;                          // 256
    int* boff      = bsum + 256;                         // 256
    unsigned* partial_out = (unsigned*)(boff + 256);     // CH*NP
    unsigned* partial_in  = partial_out + (size_t)CH * NP; // CH*NP
    unsigned short* csr = (unsigned short*)(partial_in + (size_t)CH * NP); // E u16

    // ---- atomic-free CSR build + norms + x0 + W fragment packs (9 launches) ----
    k_hist<<<2 * CH, 256, 0, stream>>>(src, dst, partial_out, partial_in, E, NP, Ec);
    k_merge<<<(NP + 31) / 32, 256, 0, stream>>>(partial_out, partial_in, cnt_in,
                                                norm_out, norm_in, nid, z, emb, zt,
                                                xA, N, NP);
    k_scan_local<<<NB, 256, 0, stream>>>(cnt_in, excl, bsum, N);
    k_scan_bsum_prep<<<1 + 128 + 32, 256, 0, stream>>>(bsum, boff, NB, W0, W1,
                                                       WF0, WF1, g);
    k_fill<<<CH, 256, 0, stream>>>(src, dst, excl, boff, partial_in, csr, N, E, NP, Ec);

    int gg_blocks = (N + 15) / 16;

    // layer 0: xA -> xB (fused gather+GEMM, 16 nodes/block)
    k_gather_gemm<<<gg_blocks, 256, 0, stream>>>(xA, norm_in, csr, excl, boff, cnt_in,
                                                 WF0, b0, norm_out, xB, N);
    // layer 1: xB -> xA
    k_gather_gemm<<<gg_blocks, 256, 0, stream>>>(xB, norm_in, csr, excl, boff, cnt_in,
                                                 WF1, b1, norm_out, xA, N);
    // layer 2: gather fused with SumPool (GEMM commuted past pool via linearity)
    k_gather_pool<<<gg_blocks, 256, 0, stream>>>(xA, norm_in, csr, excl, boff, cnt_in,
                                                 gid, g, N);

    // tiny per-graph MLP head
    k_head<<<NG, 256, 0, stream>>>(g, gid, W2, b2, l1W, l1b, l2W, l2b, out, N);
}

// Round 9
// 269.877 us; speedup vs baseline: 1.1237x; 1.0519x over previous
//
#include <hip/hip_runtime.h>
#include <hip/hip_bf16.h>

// SEAL GCN: 3x GraphConv(norm=both) -> SumPool(graph_id sorted) -> MLP(128->128 relu ->200)
// N=50000, E=800000, feat=128, 512 graphs.
// R19 = exact revert to R14 (session best, 276.3us). R15-R18 variations all regressed:
//      chunked gather (-27us), padded branch-free gather (-9), prepass fusions (-8).
//      Gathers are L2-miss-concurrency bound (FETCH 73MB/gather via L3, immune to
//      occupancy and ILP depth); prepass is balanced (fill+buildx overlapped in one
//      launch). Locking in best for reproducibility; roofline call next round if flat.

#define FEAT 128
#define NG 512
#define CH 128       // edge chunks for hist/fill
#define NPMAX 12544  // max node-quads (N<=50176); 50KB static LDS
#define LDW 136      // LDS row stride in ushorts (bf16): 2-way-free banks for b128

typedef __attribute__((ext_vector_type(8))) short bf16x8;
typedef __attribute__((ext_vector_type(4))) float f32x4;

__device__ __forceinline__ float bf2f(unsigned short u) {
    union { unsigned int i; float f; } v; v.i = ((unsigned int)u) << 16; return v.f;
}
__device__ __forceinline__ unsigned short f2bf(float f) {
    unsigned int u = __float_as_uint(f);
    return (unsigned short)((u + 0x7FFFu + ((u >> 16) & 1u)) >> 16);  // RNE
}
__device__ __forceinline__ float lo16(unsigned u) { return __uint_as_float(u << 16); }
__device__ __forceinline__ float hi16(unsigned u) { return __uint_as_float(u & 0xFFFF0000u); }

// ---------------- chunked full-range histogram, packed u8, zero global atomics ----------------
__global__ __launch_bounds__(256) void k_hist(
        const int* __restrict__ src, const int* __restrict__ dst,
        unsigned* __restrict__ partial_out, unsigned* __restrict__ partial_in,
        int E, int NP, int Ec) {
    __shared__ unsigned h[NPMAX];
    int tid = threadIdx.x;
    int b = blockIdx.x;
    int c = b & (CH - 1);
    const int* __restrict__ arr = (b < CH) ? src : dst;
    unsigned* __restrict__ outp = ((b < CH) ? partial_out : partial_in) + (size_t)c * NP;
    for (int i = tid; i < NP; i += 256) h[i] = 0;
    __syncthreads();
    int e0 = c * Ec, e1 = min(E, e0 + Ec);
    for (int e = e0 + tid; e < e1; e += 256) {
        int v = arr[e];
        atomicAdd(&h[v >> 2], 1u << ((v & 3) * 8));
    }
    __syncthreads();
    for (int i = tid; i < NP; i += 256) outp[i] = h[i];
}

// ---------------- merge partials: tiled parallel scan (32 quads x 128 chunks / block) ----------
// Replaces serial-128 chunk walk: per-block LDS tile, 8 threads/quad segmented scan.
// partial_in[c][w] <- exclusive prefix over chunks; totals -> cnt_in/norm_in/norm_out.
__global__ __launch_bounds__(256) void k_merge(
        unsigned* __restrict__ partial_out, unsigned* __restrict__ partial_in,
        int* __restrict__ cnt_in, float* __restrict__ norm_out,
        float* __restrict__ norm_in, int N, int NP) {
    __shared__ unsigned tile[CH][33];   // 128 x 33 u32 = 16.9KB (pad -> 2-way max)
    __shared__ unsigned sums[32][9];    // [quad][seg 0..7, total_in at 8]
    int q0 = blockIdx.x * 32;
    int tid = threadIdx.x;
    int qd = tid & 31, k = tid >> 5;    // 8 segs x 16 chunks per quad

    // ---- pass 1: partial_in -> exclusive prefix + totals ----
    for (int idx = tid; idx < 32 * CH; idx += 256) {
        int c = idx >> 5, q = idx & 31;
        unsigned v = 0;
        if (q0 + q < NP) v = partial_in[(size_t)c * NP + q0 + q];
        tile[c][q] = v;
    }
    __syncthreads();
    unsigned loc = 0;
    #pragma unroll
    for (int i = 0; i < 16; i++) loc += tile[k * 16 + i][qd];
    sums[qd][k] = loc;
    __syncthreads();
    if (k == 0) {
        unsigned r = 0;
        #pragma unroll
        for (int j = 0; j < 8; j++) { unsigned v = sums[qd][j]; sums[qd][j] = r; r += v; }
        sums[qd][8] = r;   // total in-degree (packed u8 x4)
    }
    __syncthreads();
    unsigned run = sums[qd][k];
    #pragma unroll
    for (int i = 0; i < 16; i++) {
        unsigned v = tile[k * 16 + i][qd];
        tile[k * 16 + i][qd] = run;
        run += v;
    }
    __syncthreads();
    for (int idx = tid; idx < 32 * CH; idx += 256) {
        int c = idx >> 5, q = idx & 31;
        if (q0 + q < NP) partial_in[(size_t)c * NP + q0 + q] = tile[c][q];
    }
    __syncthreads();

    // ---- pass 2: partial_out totals only ----
    for (int idx = tid; idx < 32 * CH; idx += 256) {
        int c = idx >> 5, q = idx & 31;
        unsigned v = 0;
        if (q0 + q < NP) v = partial_out[(size_t)c * NP + q0 + q];
        tile[c][q] = v;
    }
    __syncthreads();
    unsigned loco = 0;
    #pragma unroll
    for (int i = 0; i < 16; i++) loco += tile[k * 16 + i][qd];
    sums[qd][k] = loco;   // safe: prefix values already consumed; [8] untouched
    __syncthreads();
    if (k == 0) {
        unsigned tot = 0;
        #pragma unroll
        for (int j = 0; j < 8; j++) tot += sums[qd][j];
        unsigned rin = sums[qd][8];
        int w = q0 + qd;
        if (w < NP) {
            #pragma unroll
            for (int j = 0; j < 4; j++) {
                int node = w * 4 + j;
                if (node < N) {
                    unsigned di = (rin >> (j * 8)) & 255u;
                    unsigned dd = (tot >> (j * 8)) & 255u;
                    cnt_in[node]   = (int)di;
                    norm_in[node]  = rsqrtf(fmaxf((float)di, 1.0f));
                    norm_out[node] = rsqrtf(fmaxf((float)dd, 1.0f));
                }
            }
        }
    }
}

// ---------------- 2-level exclusive scan of cnt_in -> row_start ----------------
__global__ void k_scan_local(const int* __restrict__ cnt, int* __restrict__ excl,
                             int* __restrict__ bsum, int N) {
    __shared__ int s[256];
    int x = threadIdx.x;
    int i = blockIdx.x * 256 + x;
    int v = (i < N) ? cnt[i] : 0;
    s[x] = v;
    __syncthreads();
    for (int off = 1; off < 256; off <<= 1) {
        int t = (x >= off) ? s[x - off] : 0;
        __syncthreads();
        s[x] += t;
        __syncthreads();
    }
    if (i < N) excl[i] = s[x] - v;
    if (x == 255) bsum[blockIdx.x] = s[255];
}

// block 0: scan of block sums; blocks 1..128: pack W0,W1 -> bf16 MFMA B-fragment order
// WF[f][lane][e] with f=nt*4+fi, lane=q*16+c: value = W[k*128+n], n=nt*16+c, k=fi*32+q*8+e
__global__ void k_scan_bsum_prep(int* __restrict__ bsum, int* __restrict__ boff, int nb,
                                 const float* __restrict__ W0, const float* __restrict__ W1,
                                 unsigned short* __restrict__ WF0, unsigned short* __restrict__ WF1) {
    if (blockIdx.x == 0) {
        __shared__ int s[256];
        int x = threadIdx.x;
        int v = (x < nb) ? bsum[x] : 0;
        s[x] = v;
        __syncthreads();
        for (int off = 1; off < 256; off <<= 1) {
            int t = (x >= off) ? s[x - off] : 0;
            __syncthreads();
            s[x] += t;
            __syncthreads();
        }
        if (x < nb) boff[x] = s[x] - v;
    } else {
        int t = ((int)blockIdx.x - 1) * 256 + threadIdx.x;  // 0..32767
        const float* __restrict__ W = (t < 16384) ? W0 : W1;
        unsigned short* __restrict__ WF = (t < 16384) ? WF0 : WF1;
        int tt = t & 16383;
        int f = tt >> 9, l = (tt >> 3) & 63, e = tt & 7;
        int n = (f >> 2) * 16 + (l & 15);
        int k = (f & 3) * 32 + (l >> 4) * 8 + e;
        WF[tt] = f2bf(W[k * 128 + n]);
    }
}

__global__ void k_add_off(int* __restrict__ row_start, const int* __restrict__ boff,
                          float* __restrict__ g, int N) {
    int i = blockIdx.x * blockDim.x + threadIdx.x;
    int stride = gridDim.x * blockDim.x;
    if (i < N) row_start[i] += boff[i >> 8];
    for (int j = i; j < NG * FEAT; j += stride) g[j] = 0.f;  // zero pooled accum
}

// ---------------- chunked CSR fill (LDS cursors, packed u8, u16 csr) + build x0 ----------------
__global__ __launch_bounds__(256) void k_fill_bx(
        const int* __restrict__ src, const int* __restrict__ dst,
        const int* __restrict__ row_start, const unsigned* __restrict__ partial_in,
        unsigned short* __restrict__ csr,
        const int* __restrict__ nid, const int* __restrict__ z,
        const float* __restrict__ emb, const float* __restrict__ zt,
        const float* __restrict__ nout, unsigned short* __restrict__ x,
        int N, int E, int NP, int Ec) {
    if ((int)blockIdx.x < CH) {
        __shared__ unsigned cur[NPMAX];
        int tid = threadIdx.x;
        int c = blockIdx.x;
        const unsigned* __restrict__ pre = partial_in + (size_t)c * NP;
        for (int i = tid; i < NP; i += 256) cur[i] = pre[i];
        __syncthreads();
        int e0 = c * Ec, e1 = min(E, e0 + Ec);
        for (int e = e0 + tid; e < e1; e += 256) {
            int d = dst[e], s = src[e];
            int sh = (d & 3) * 8;
            unsigned t = atomicAdd(&cur[d >> 2], 1u << sh);
            int off = (int)((t >> sh) & 255u);
            csr[row_start[d] + off] = (unsigned short)s;
        }
    } else {
        int tid = ((int)blockIdx.x - CH) * 256 + threadIdx.x;
        int i = tid >> 5, q = tid & 31;
        if (i < N) {
            float4 v;
            if (q < 16) v = ((const float4*)emb)[(size_t)nid[i] * 16 + q];
            else        v = ((const float4*)zt)[(size_t)z[i] * 16 + (q - 16)];
            float w = nout[i];
            ushort4 u;
            u.x = f2bf(v.x * w); u.y = f2bf(v.y * w);
            u.z = f2bf(v.z * w); u.w = f2bf(v.w * w);
            ((ushort4*)x)[(size_t)i * 32 + q] = u;
        }
    }
}

// ---------------- gather core: b128 loads, 16 lanes/node, 8-deep ILP ----------------
#define ACC8(u)                                                                  \
    a0 += lo16(u.x); a1 += hi16(u.x); a2 += lo16(u.y); a3 += hi16(u.y);          \
    a4 += lo16(u.z); a5 += hi16(u.z); a6 += lo16(u.w); a7 += hi16(u.w);

#define GATHER_LOOP                                                              \
    {                                                                            \
        int base = row_start[node];                                              \
        int n = cnt_in[node];                                                    \
        const uint4* xp = (const uint4*)x;  /* row = 16 uint4 */                 \
        for (int j0 = 0; j0 < n; j0 += 16) {                                     \
            int rem = n - j0;                                                    \
            int m = rem < 16 ? rem : 16;                                         \
            int e = (int)csr[base + j0 + (ql < m ? ql : 0)];                     \
            int j = 0;                                                           \
            for (; j + 8 <= m; j += 8) {                                         \
                int s0 = __shfl(e, j + 0, 16), s1 = __shfl(e, j + 1, 16);        \
                int s2 = __shfl(e, j + 2, 16), s3 = __shfl(e, j + 3, 16);        \
                int s4 = __shfl(e, j + 4, 16), s5 = __shfl(e, j + 5, 16);        \
                int s6 = __shfl(e, j + 6, 16), s7 = __shfl(e, j + 7, 16);        \
                uint4 u0 = xp[(size_t)s0 * 16 + ql];                             \
                uint4 u1 = xp[(size_t)s1 * 16 + ql];                             \
                uint4 u2 = xp[(size_t)s2 * 16 + ql];                             \
                uint4 u3 = xp[(size_t)s3 * 16 + ql];                             \
                uint4 u4 = xp[(size_t)s4 * 16 + ql];                             \
                uint4 u5 = xp[(size_t)s5 * 16 + ql];                             \
                uint4 u6 = xp[(size_t)s6 * 16 + ql];                             \
                uint4 u7 = xp[(size_t)s7 * 16 + ql];                             \
                ACC8(u0) ACC8(u1) ACC8(u2) ACC8(u3)                              \
                ACC8(u4) ACC8(u5) ACC8(u6) ACC8(u7)                              \
            }                                                                    \
            for (; j + 4 <= m; j += 4) {                                         \
                int s0 = __shfl(e, j + 0, 16), s1 = __shfl(e, j + 1, 16);        \
                int s2 = __shfl(e, j + 2, 16), s3 = __shfl(e, j + 3, 16);        \
                uint4 u0 = xp[(size_t)s0 * 16 + ql];                             \
                uint4 u1 = xp[(size_t)s1 * 16 + ql];                             \
                uint4 u2 = xp[(size_t)s2 * 16 + ql];                             \
                uint4 u3 = xp[(size_t)s3 * 16 + ql];                             \
                ACC8(u0) ACC8(u1) ACC8(u2) ACC8(u3)                              \
            }                                                                    \
            for (; j < m; j++) {                                                 \
                int s = __shfl(e, j, 16);                                        \
                uint4 u = xp[(size_t)s * 16 + ql];                               \
                ACC8(u)                                                          \
            }                                                                    \
        }                                                                        \
    }

// ---------------- fused gather + MFMA GEMM, 16 nodes/block ----------------
// Gather: all 256 threads = 16 nodes x 16 lanes, single round. GEMM: 16-row tile; all 4
// waves share the same A-frags from LDS; wave w computes column-tiles {2w, 2w+1}.
// launch_bounds(256,8): cap VGPR<=64 -> 8 waves/SIMD resident (latency-bound gather).
__global__ __launch_bounds__(256, 8) void k_gather_gemm(
        const unsigned short* __restrict__ x, const float* __restrict__ nin,
        const unsigned short* __restrict__ csr, const int* __restrict__ row_start,
        const int* __restrict__ cnt_in, const unsigned short* __restrict__ WF,
        const float* __restrict__ bias, const float* __restrict__ nout,
        unsigned short* __restrict__ y, int N) {
    __shared__ unsigned short As[16 * LDW];  // 4.3KB
    int tid = threadIdx.x;
    int nb = blockIdx.x * 16;
    int ql = tid & 15;
    int nl = tid >> 4;
    int node = nb + nl;

    float a0 = 0.f, a1 = 0.f, a2 = 0.f, a3 = 0.f;
    float a4 = 0.f, a5 = 0.f, a6 = 0.f, a7 = 0.f;
    if (node < N) {
        GATHER_LOOP
        float ni = nin[node];
        a0 *= ni; a1 *= ni; a2 *= ni; a3 *= ni;
        a4 *= ni; a5 *= ni; a6 *= ni; a7 *= ni;
    }
    uint4 o;
    o.x = (unsigned)f2bf(a0) | ((unsigned)f2bf(a1) << 16);
    o.y = (unsigned)f2bf(a2) | ((unsigned)f2bf(a3) << 16);
    o.z = (unsigned)f2bf(a4) | ((unsigned)f2bf(a5) << 16);
    o.w = (unsigned)f2bf(a6) | ((unsigned)f2bf(a7) << 16);
    *(uint4*)(As + nl * LDW + ql * 8) = o;
    __syncthreads();

    int lane = tid & 63;
    int wv = tid >> 6;
    int c = lane & 15, q = lane >> 4;

    // shared 16-row A-fragments (identical across waves: LDS broadcast)
    const unsigned short* ap = As + c * LDW + q * 8;
    bf16x8 fa0 = *(const bf16x8*)(ap);
    bf16x8 fa1 = *(const bf16x8*)(ap + 32);
    bf16x8 fa2 = *(const bf16x8*)(ap + 64);
    bf16x8 fa3 = *(const bf16x8*)(ap + 96);
    const bf16x8* __restrict__ wf = (const bf16x8*)WF;
    __syncthreads();  // A-frags in regs; safe to overwrite As with outputs

    #pragma unroll
    for (int t = 0; t < 2; t++) {
        int nt = wv * 2 + t;
        bf16x8 fb0 = wf[(nt * 4 + 0) * 64 + lane];
        bf16x8 fb1 = wf[(nt * 4 + 1) * 64 + lane];
        bf16x8 fb2 = wf[(nt * 4 + 2) * 64 + lane];
        bf16x8 fb3 = wf[(nt * 4 + 3) * 64 + lane];
        float bb = bias[nt * 16 + c];
        f32x4 acc = {bb, bb, bb, bb};
        acc = __builtin_amdgcn_mfma_f32_16x16x32_bf16(fa0, fb0, acc, 0, 0, 0);
        acc = __builtin_amdgcn_mfma_f32_16x16x32_bf16(fa1, fb1, acc, 0, 0, 0);
        acc = __builtin_amdgcn_mfma_f32_16x16x32_bf16(fa2, fb2, acc, 0, 0, 0);
        acc = __builtin_amdgcn_mfma_f32_16x16x32_bf16(fa3, fb3, acc, 0, 0, 0);
        #pragma unroll
        for (int rr = 0; rr < 4; rr++) {
            int row = q * 4 + rr;
            float s = nout[min(nb + row, N - 1)];
            As[row * LDW + nt * 16 + c] = f2bf(fmaxf(acc[rr], 0.f) * s);
        }
    }
    __syncthreads();

    // coalesced store: 16 rows x 128 u16 = 256 x ushort4x2
    {
        int row = tid >> 4, seg = tid & 15;
        int nd = nb + row;
        if (nd < N) {
            const ushort4* p = (const ushort4*)(As + row * LDW + seg * 8);
            ushort4* d = (ushort4*)(y + (size_t)nd * 128 + seg * 8);
            d[0] = p[0]; d[1] = p[1];
        }
    }
}

// ---------------- fused layer-2 gather + SumPool: g[gid] += (A_hat x)[node] ----------------
// graph_id sorted -> per-node LDS rows, then non-atomic segmented reduction over the
// sorted gid runs (<=16 per block); one coalesced global-atomic set per run-half.
__global__ __launch_bounds__(256, 8) void k_gather_pool(
        const unsigned short* __restrict__ x, const float* __restrict__ nin,
        const unsigned short* __restrict__ csr, const int* __restrict__ row_start,
        const int* __restrict__ cnt_in, const int* __restrict__ gid,
        float* __restrict__ g, int N) {
    __shared__ __align__(16) float gl[16][132];  // per-node partials, +4 pad
    __shared__ int slots[16];
    int tid = threadIdx.x;
    int nb = blockIdx.x * 16;
    int ql = tid & 15;
    int nl = tid >> 4;
    int node = nb + nl;

    float a0 = 0.f, a1 = 0.f, a2 = 0.f, a3 = 0.f;
    float a4 = 0.f, a5 = 0.f, a6 = 0.f, a7 = 0.f;
    int slot = -1;
    if (node < N) {
        GATHER_LOOP
        float ni = nin[node];
        a0 *= ni; a1 *= ni; a2 *= ni; a3 *= ni;
        a4 *= ni; a5 *= ni; a6 *= ni; a7 *= ni;
        slot = gid[node];
    }
    float4* row = (float4*)&gl[nl][ql * 8];
    row[0] = make_float4(a0, a1, a2, a3);
    row[1] = make_float4(a4, a5, a6, a7);
    if (ql == 0) slots[nl] = slot;
    __syncthreads();

    int h = tid >> 7;       // 0/1: nodes 0-7 / 8-15
    int j = tid & 127;
    int prev = -1;
    float acc = 0.f;
    #pragma unroll
    for (int i = h * 8; i < h * 8 + 8; i++) {
        int s = slots[i];
        if (s != prev) {
            if (prev >= 0) atomicAdd(&g[(size_t)prev * FEAT + j], acc);
            acc = 0.f;
            prev = s;
        }
        acc += gl[i][j];
    }
    if (prev >= 0) atomicAdd(&g[(size_t)prev * FEAT + j], acc);
}

// ---------------- head: ys = g@W2 + cnt*b2 ; out = relu(ys@l1W+l1b)@l2W+l2b ----------------
__global__ __launch_bounds__(256) void k_head(
        const float* __restrict__ g, const int* __restrict__ gid,
        const float* __restrict__ W2, const float* __restrict__ b2,
        const float* __restrict__ l1W, const float* __restrict__ l1b,
        const float* __restrict__ l2W, const float* __restrict__ l2b,
        float* __restrict__ out, int N) {
    __shared__ float gs[128];
    __shared__ float ys[128];
    __shared__ float hs[128];
    int gi = blockIdx.x, tid = threadIdx.x;

    int lo = 0, hi = N;
    while (lo < hi) { int m = (lo + hi) >> 1; if (gid[m] < gi) lo = m + 1; else hi = m; }
    int s0 = lo;
    lo = 0; hi = N;
    while (lo < hi) { int m = (lo + hi) >> 1; if (gid[m] < gi + 1) lo = m + 1; else hi = m; }
    float cnt = (float)(lo - s0);

    if (tid < 128) gs[tid] = g[(size_t)gi * FEAT + tid];
    __syncthreads();
    if (tid < 128) {
        float a = cnt * b2[tid];
        for (int k = 0; k < 128; k++) a += gs[k] * W2[(size_t)k * 128 + tid];
        ys[tid] = a;
    }
    __syncthreads();
    if (tid < 128) {
        float a = l1b[tid];
        for (int k = 0; k < 128; k++) a += ys[k] * l1W[(size_t)k * 128 + tid];
        hs[tid] = fmaxf(a, 0.f);
    }
    __syncthreads();
    if (tid < 200) {
        float a = l2b[tid];
        for (int k = 0; k < 128; k++) a += hs[k] * l2W[(size_t)k * 200 + tid];
        out[(size_t)gi * 200 + tid] = a;
    }
}

extern "C" void kernel_launch(void* const* d_in, const int* in_sizes, int n_in,
                              void* d_out, int out_size, void* d_ws, size_t ws_size,
                              hipStream_t stream) {
    const int*   nid = (const int*)d_in[0];
    const int*   z   = (const int*)d_in[1];
    const int*   src = (const int*)d_in[2];
    const int*   dst = (const int*)d_in[3];
    const int*   gid = (const int*)d_in[4];
    const float* emb = (const float*)d_in[5];
    const float* zt  = (const float*)d_in[6];
    const float* W0  = (const float*)d_in[7];
    const float* b0  = (const float*)d_in[8];
    const float* W1  = (const float*)d_in[9];
    const float* b1  = (const float*)d_in[10];
    const float* W2  = (const float*)d_in[11];
    const float* b2  = (const float*)d_in[12];
    const float* l1W = (const float*)d_in[13];
    const float* l1b = (const float*)d_in[14];
    const float* l2W = (const float*)d_in[15];
    const float* l2b = (const float*)d_in[16];
    float* out = (float*)d_out;

    const int N = in_sizes[0];
    const int E = in_sizes[2];
    const int NB = (N + 255) / 256;     // scan blocks (<=256 required)
    const int NP = (N + 3) / 4;         // node-quads (<= NPMAX)
    const int Ec = (E + CH - 1) / CH;   // edges per chunk

    // ---- workspace ----
    size_t NA = (size_t)((N + 63) & ~63);
    float* norm_out = (float*)d_ws;                      // NA
    float* norm_in  = norm_out + NA;                     // NA
    float* g        = norm_in + NA;                      // NG*FEAT fp32 pooled accum
    unsigned short* xA  = (unsigned short*)(g + (size_t)NG * FEAT);  // N*128 bf16
    unsigned short* xB  = xA + (size_t)N * FEAT;         // N*128 bf16
    unsigned short* WF0 = xB + (size_t)N * FEAT;         // 128*128 bf16 (fragment order)
    unsigned short* WF1 = WF0 + 128 * 128;               // 128*128 bf16
    int* cnt_in    = (int*)(WF1 + 128 * 128);            // NA
    int* row_start = cnt_in + NA;                        // NA
    int* bsum      = row_start + NA;                     // 256
    int* boff      = bsum + 256;                         // 256
    unsigned* partial_out = (unsigned*)(boff + 256);     // CH*NP
    unsigned* partial_in  = partial_out + (size_t)CH * NP; // CH*NP
    unsigned short* csr = (unsigned short*)(partial_in + (size_t)CH * NP); // E u16

    // ---- atomic-free CSR build + norms + W fragment packs ----
    k_hist<<<2 * CH, 256, 0, stream>>>(src, dst, partial_out, partial_in, E, NP, Ec);
    k_merge<<<(NP + 31) / 32, 256, 0, stream>>>(partial_out, partial_in, cnt_in,
                                                norm_out, norm_in, N, NP);
    k_scan_local<<<NB, 256, 0, stream>>>(cnt_in, row_start, bsum, N);
    k_scan_bsum_prep<<<1 + 128, 256, 0, stream>>>(bsum, boff, NB, W0, W1, WF0, WF1);
    k_add_off<<<NB, 256, 0, stream>>>(row_start, boff, g, N);
    int XB = (N * 32 + 255) / 256;
    k_fill_bx<<<CH + XB, 256, 0, stream>>>(src, dst, row_start, partial_in, csr,
                                           nid, z, emb, zt, norm_out, xA, N, E, NP, Ec);

    int gg_blocks = (N + 15) / 16;

    // layer 0: xA -> xB (fused gather+GEMM, 16 nodes/block)
    k_gather_gemm<<<gg_blocks, 256, 0, stream>>>(xA, norm_in, csr, row_start, cnt_in,
                                                 WF0, b0, norm_out, xB, N);
    // layer 1: xB -> xA
    k_gather_gemm<<<gg_blocks, 256, 0, stream>>>(xB, norm_in, csr, row_start, cnt_in,
                                                 WF1, b1, norm_out, xA, N);
    // layer 2: gather fused with SumPool (GEMM commuted past pool via linearity)
    k_gather_pool<<<gg_blocks, 256, 0, stream>>>(xA, norm_in, csr, row_start, cnt_in,
                                                 gid, g, N);

    // fused pool + MLP head
    k_head<<<NG, 256, 0, stream>>>(g, gid, W2, b2, l1W, l1b, l2W, l2b, out, N);
}